// Round 5
// baseline (978.685 us; speedup 1.0000x reference)
//
#include <hip/hip_runtime.h>
#include <hip/hip_bf16.h>

typedef __bf16 bf16x8 __attribute__((ext_vector_type(8)));
typedef float  f32x4  __attribute__((ext_vector_type(4)));

#define T_   3
#define N_   200000
#define C_   256
#define B_   512
#define EPSb 1e-5f
#define NTILES 9375   // 3 * 200000/64

__device__ __forceinline__ unsigned enc_f(float f){
  unsigned u = __float_as_uint(f);
  return (u & 0x80000000u) ? ~u : (u | 0x80000000u);
}
__device__ __forceinline__ float dec_f(unsigned k){
  unsigned u = (k & 0x80000000u) ? (k ^ 0x80000000u) : ~k;
  return __uint_as_float(u);
}

// raw barrier WITHOUT vmcnt drain (lets prefetch global loads stay in flight)
__device__ __forceinline__ void barrier_nodrain(){
  __builtin_amdgcn_sched_barrier(0);
  asm volatile("s_waitcnt lgkmcnt(0)" ::: "memory");
  __builtin_amdgcn_s_barrier();
  __builtin_amdgcn_sched_barrier(0);
}

// device-scope generation barrier (all gridDim blocks must be co-resident)
__device__ __forceinline__ void gridbar(unsigned* cnt, unsigned* gen, unsigned nblk){
  __threadfence();
  __syncthreads();
  if (threadIdx.x == 0){
    unsigned g = __hip_atomic_load(gen, __ATOMIC_RELAXED, __HIP_MEMORY_SCOPE_AGENT);
    unsigned a = __hip_atomic_fetch_add(cnt, 1u, __ATOMIC_ACQ_REL, __HIP_MEMORY_SCOPE_AGENT);
    if (a == nblk - 1u){
      __hip_atomic_store(cnt, 0u, __ATOMIC_RELAXED, __HIP_MEMORY_SCOPE_AGENT);
      __hip_atomic_store(gen, g + 1u, __ATOMIC_RELEASE, __HIP_MEMORY_SCOPE_AGENT);
    } else {
      while (__hip_atomic_load(gen, __ATOMIC_ACQUIRE, __HIP_MEMORY_SCOPE_AGENT) == g)
        __builtin_amdgcn_s_sleep(2);
    }
  }
  __syncthreads();
  __threadfence();
}

// ---------------- prep: Wl transpose->bf16, cvec, zero-fill (one kernel)
__global__ void kprep(const float* __restrict__ Wl, __hip_bfloat16* __restrict__ wlt,
                      const float* __restrict__ Wr, const float* __restrict__ bl,
                      const float* __restrict__ br, const float* __restrict__ gtok,
                      float* __restrict__ cvec, float* __restrict__ zr){
  __shared__ float tile[64][65];
  __shared__ float gt[256];
  int blk = blockIdx.x, tid = threadIdx.x;
  if (blk < 48){
    int t = blk / 16, rem = blk % 16;
    int k0 = (rem >> 2)*64, c0 = (rem & 3)*64;
    int lc = tid & 63, lr0 = tid >> 6;
    #pragma unroll
    for (int q = 0; q < 16; q++){
      int lr = lr0*16 + q;
      tile[lr][lc] = Wl[t*65536 + (k0+lr)*256 + (c0+lc)];
    }
    __syncthreads();
    #pragma unroll
    for (int q = 0; q < 16; q++){
      int lr = lr0*16 + q;
      wlt[t*65536 + (c0+lr)*256 + (k0+lc)] = __float2bfloat16(tile[lc][lr]);
    }
  } else if (blk < 51){
    int t = blk - 48, c = tid;
    gt[tid] = gtok[t*256 + tid];
    __syncthreads();
    const float* wr = Wr + t*65536 + c;
    float a0=0.f,a1=0.f,a2=0.f,a3=0.f;
    #pragma unroll 2
    for (int k = 0; k < 256; k += 4){
      a0 += gt[k]  *wr[k*256];
      a1 += gt[k+1]*wr[(k+1)*256];
      a2 += gt[k+2]*wr[(k+2)*256];
      a3 += gt[k+3]*wr[(k+3)*256];
    }
    cvec[t*256 + c] = a0+a1+a2+a3 + bl[t*256+c] + br[t*256+c];
  } else {
    // zero region: gacc(393216)+den(1536)+mkey(1536)+bns(2048)+bar(16) floats
    for (int i = (blk-51)*256 + tid; i < 398352; i += (gridDim.x-51)*256) zr[i] = 0.f;
  }
}

// ---------------- big pass (contiguous ranges): e_approx = att.lrelu(x@Wl+cvec)
__global__ __launch_bounds__(512, 2)
void k1(const float* __restrict__ x, const __hip_bfloat16* __restrict__ wlt,
        const float* __restrict__ cvec, const float* __restrict__ att,
        const int* __restrict__ batch, float* __restrict__ e_out,
        unsigned* __restrict__ mkey){
  __shared__ __align__(16) __hip_bfloat16 Abuf[64][256];
  __shared__ float elds[4][64];
  const int tid = threadIdx.x;
  const int w = tid >> 6, l = tid & 63;
  const int wcol = w & 3, wrow = w >> 2;
  const int l15 = l & 15, l4 = l >> 4;
  const int srow = tid >> 3;
  const int sc   = tid & 7;
  const int sx   = srow & 7;

  bf16x8 bfr[8][4];
  float cv[4], at[4];
  int cur_t = -1;

  const int bid = blockIdx.x;
  const int nt = 18 + (bid < 159 ? 1 : 0);
  const int g0 = bid*18 + (bid < 159 ? bid : 159);

  f32x4 rg[8];
  {
    int t = g0 / 3125, tile = g0 % 3125;
    const float* xrow = x + (size_t)t*N_*256 + (size_t)(tile*64 + srow)*256;
    #pragma unroll
    for (int q = 0; q < 4; q++){
      int cs = (q*8 + sc) ^ sx;
      rg[2*q]   = *(const f32x4*)(xrow + cs*8);
      rg[2*q+1] = *(const f32x4*)(xrow + cs*8 + 4);
    }
  }

  for (int it = 0; it < nt; ++it){
    const int gt = g0 + it;
    const int t = gt / 3125, tile = gt % 3125;
    if (t != cur_t){
      cur_t = t;
      const __hip_bfloat16* WT = wlt + t*65536;
      #pragma unroll
      for (int fn = 0; fn < 4; fn++){
        int col = wcol*64 + fn*16 + l15;
        cv[fn] = cvec[t*256 + col];
        at[fn] = att[t*256 + col];
        #pragma unroll
        for (int ks = 0; ks < 8; ks++)
          bfr[ks][fn] = *(const bf16x8*)(WT + col*256 + ks*32 + l4*8);
      }
    }
    // stage rg -> LDS (swizzled slots)
    #pragma unroll
    for (int q = 0; q < 4; q++){
      bf16x8 v;
      #pragma unroll
      for (int j = 0; j < 4; j++){ v[j] = (__bf16)rg[2*q][j]; v[4+j] = (__bf16)rg[2*q+1][j]; }
      *(bf16x8*)(&Abuf[srow][(q*8 + sc)*8]) = v;
    }
    // prefetch next tile (stays in flight across the raw barrier)
    if (it + 1 < nt){
      int gn = gt + 1;
      int tn = gn / 3125, tilen = gn % 3125;
      const float* xrow = x + (size_t)tn*N_*256 + (size_t)(tilen*64 + srow)*256;
      #pragma unroll
      for (int q = 0; q < 4; q++){
        int cs = (q*8 + sc) ^ sx;
        rg[2*q]   = *(const f32x4*)(xrow + cs*8);
        rg[2*q+1] = *(const f32x4*)(xrow + cs*8 + 4);
      }
    }
    barrier_nodrain();

    f32x4 acc[2][4];
    #pragma unroll
    for (int fm = 0; fm < 2; fm++)
      #pragma unroll
      for (int fn = 0; fn < 4; fn++)
        acc[fm][fn] = (f32x4){0.f,0.f,0.f,0.f};

    #pragma unroll
    for (int ks = 0; ks < 8; ks++){
      bf16x8 a8[2];
      #pragma unroll
      for (int fm = 0; fm < 2; fm++){
        int row  = wrow*32 + fm*16 + l15;
        int slot = (ks*4 + l4) ^ (row & 7);
        a8[fm] = *(const bf16x8*)(&Abuf[row][slot*8]);
      }
      #pragma unroll
      for (int fm = 0; fm < 2; fm++)
        #pragma unroll
        for (int fn = 0; fn < 4; fn++)
          acc[fm][fn] = __builtin_amdgcn_mfma_f32_16x16x32_bf16(a8[fm], bfr[ks][fn], acc[fm][fn], 0, 0, 0);
    }

    #pragma unroll
    for (int fm = 0; fm < 2; fm++){
      #pragma unroll
      for (int r = 0; r < 4; r++){
        float v = 0.f;
        #pragma unroll
        for (int fn = 0; fn < 4; fn++){
          float xv = acc[fm][fn][r] + cv[fn];
          xv = (xv > 0.f) ? xv : 0.2f*xv;
          v += xv * at[fn];
        }
        v += __shfl_xor(v, 1);
        v += __shfl_xor(v, 2);
        v += __shfl_xor(v, 4);
        v += __shfl_xor(v, 8);
        if (l15 == 0) elds[wcol][wrow*32 + fm*16 + l4*4 + r] = v;
      }
    }
    barrier_nodrain();

    if (tid < 64){
      float ef = elds[0][tid] + elds[1][tid] + elds[2][tid] + elds[3][tid];
      int n = tile*64 + tid;
      e_out[t*N_ + n] = ef;
      int b = batch[t*N_ + n];
      float m = ef;
      #pragma unroll
      for (int off = 1; off < 64; off <<= 1){
        float up = __shfl_up(m, off);
        int   bu = __shfl_up(b, off);
        if (tid >= off && bu == b) m = fmaxf(m, up);
      }
      int bnx = __shfl_down(b, 1);
      if (tid == 63 || b != bnx) atomicMax(&mkey[t*B_ + b], enc_f(m));
    }
  }
}

// ---------------- fused select+candidate pass: threshold scan, then exact
// fp32 xl + e + den + gacc for hits (softmax shift uses approx max: exact)
__global__ void kscan(const float* __restrict__ x, const float* __restrict__ Wl,
                      const float* __restrict__ cvec, const float* __restrict__ att,
                      const int* __restrict__ batch, const float* __restrict__ e,
                      const unsigned* __restrict__ mkey,
                      float* __restrict__ den, float* __restrict__ gacc){
  __shared__ float xs[256];
  __shared__ float red[4];
  __shared__ float ebc;
  __shared__ int hits[256];
  __shared__ int nh;
  int t = blockIdx.y;
  int tid = threadIdx.x;
  int n0 = blockIdx.x*256;
  int n = n0 + tid;
  if (tid == 0) nh = 0;
  __syncthreads();
  if (n < N_){
    float ev = e[t*N_ + n];
    int b = batch[t*N_ + n];
    float m = dec_f(mkey[t*B_ + b]);
    if (ev >= m - 30.0f){ int p = atomicAdd(&nh, 1); hits[p] = tid; }
  }
  __syncthreads();
  int cnum = nh;
  for (int i = 0; i < cnum; i++){
    int hn = n0 + hits[i];
    xs[tid] = x[(size_t)t*N_*256 + (size_t)hn*256 + tid];
    __syncthreads();
    const float* wp = Wl + t*65536 + tid;
    float a0 = 0.f, a1 = 0.f;
    #pragma unroll 8
    for (int k = 0; k < 256; k += 2){
      a0 += xs[k]   * wp[k*256];
      a1 += xs[k+1] * wp[(k+1)*256];
    }
    float xl = a0 + a1;
    float xv = xl + cvec[t*256 + tid];
    xv = (xv > 0.f) ? xv : 0.2f*xv;
    float term = xv * att[t*256 + tid];
    #pragma unroll
    for (int off = 1; off < 64; off <<= 1) term += __shfl_xor(term, off);
    if ((tid & 63) == 0) red[tid >> 6] = term;
    __syncthreads();
    if (tid == 0) ebc = red[0] + red[1] + red[2] + red[3];
    __syncthreads();
    int b = batch[t*N_ + hn];
    float m = dec_f(mkey[t*B_ + b]);
    float wv = expf(ebc - m);
    if (tid == 0) atomicAdd(&den[t*B_ + b], wv);
    atomicAdd(&gacc[t*131072 + b*256 + tid], wv * xl);
    __syncthreads();
  }
}

// ---------------- one GEMM output tile (32x64), shared-LDS variant
__device__ __forceinline__ void gemm_tile(
    const float* __restrict__ A, const float* __restrict__ addsrc,
    const float* __restrict__ ga, const float* __restrict__ gfin,
    const float* bnsc, const float* bnsh, float* __restrict__ stats,
    const float* __restrict__ W, const float* __restrict__ bias,
    float* __restrict__ out, int dotanh,
    int row0, int col0, int K, int N, int aMode, int addMode,
    float (*As)[17], float (*Ws)[64], float (*reds)[64], float (*reds2)[64])
{
  int tid = threadIdx.x;
  int tx = tid & 15, ty = tid >> 4;
  float acc[2][4] = {};
  for (int k0 = 0; k0 < K; k0 += 16){
    __syncthreads();
    #pragma unroll
    for (int q = 0; q < 2; q++){
      int idx = tid*2 + q;
      int r = idx >> 4, kk = idx & 15;
      int kg = k0 + kk;
      float v;
      if (aMode == 0)      v = A[(size_t)(row0+r)*K + kg];
      else if (aMode == 1) v = (kg < 64) ? ga[(row0+r)*64 + kg]
                               : gfin[((kg-64) >> 8)*131072 + (row0+r)*256 + ((kg-64)&255)];
      else                 v = tanhf(A[(row0+r)*512 + kg]*bnsc[kg] + bnsh[kg]);
      As[r][kk] = v;
    }
    {
      int kr = tid >> 4, cc = (tid & 15)*4;
      *(f32x4*)&Ws[kr][cc] = *(const f32x4*)&W[(size_t)(k0+kr)*N + col0 + cc];
    }
    __syncthreads();
    #pragma unroll
    for (int kk = 0; kk < 16; kk++){
      float a0 = As[ty][kk], a1 = As[ty+16][kk];
      f32x4 wv = *(const f32x4*)&Ws[kk][tx*4];
      #pragma unroll
      for (int j = 0; j < 4; j++){
        acc[0][j] += a0*wv[j];
        acc[1][j] += a1*wv[j];
      }
    }
  }
  float vout[2][4];
  #pragma unroll
  for (int i2 = 0; i2 < 2; i2++){
    int row = row0 + ty + i2*16;
    #pragma unroll
    for (int j = 0; j < 4; j++){
      int col = col0 + tx*4 + j;
      float v = acc[i2][j] + bias[col];
      if (addMode == 1) v += addsrc[(size_t)row*N + col];
      else if (addMode == 2) v += tanhf(addsrc[row*512 + col]*bnsc[col] + bnsh[col]);
      if (dotanh) v = tanhf(v);
      out[(size_t)row*N + col] = v;
      vout[i2][j] = v;
    }
  }
  if (stats){
    __syncthreads();
    #pragma unroll
    for (int j = 0; j < 4; j++){
      reds[ty][tx*4+j]  = vout[0][j] + vout[1][j];
      reds2[ty][tx*4+j] = vout[0][j]*vout[0][j] + vout[1][j]*vout[1][j];
    }
    __syncthreads();
    if (tid < 128){
      int col = tid & 63, which = tid >> 6;
      const float (*src)[64] = which ? reds2 : reds;
      float s = 0.f;
      #pragma unroll
      for (int r = 0; r < 16; r++) s += src[r][col];
      atomicAdd(&stats[which*512 + col0 + col], s);
    }
  }
}

__device__ __forceinline__ void bn_precompute(const float* __restrict__ bnsums,
                                              const float* __restrict__ bng,
                                              const float* __restrict__ bnb,
                                              float* bnsc, float* bnsh){
  int tid = threadIdx.x;
  #pragma unroll
  for (int q = 0; q < 2; q++){
    int k = q*256 + tid;
    float mu = bnsums[k] * (1.f/512.f);
    float var = bnsums[512+k] * (1.f/512.f) - mu*mu;
    float sc = bng[k] * __frsqrt_rn(var + EPSb);
    bnsc[k] = sc;
    bnsh[k] = bnb[k] - mu*sc;
  }
}

// ---------------- whole head: gfinal + 6 GEMM stages, grid-barrier chained
__global__ __launch_bounds__(256)
void khead(const float* __restrict__ ga, const float* __restrict__ gacc,
           const float* __restrict__ den, const float* __restrict__ bl,
           const float* __restrict__ bout, float* __restrict__ gout,
           const float* __restrict__ m1pw, const float* __restrict__ m1pb,
           const float* __restrict__ m1w1, const float* __restrict__ m1b1,
           const float* __restrict__ m1w2, const float* __restrict__ m1b2,
           const float* __restrict__ bn1g, const float* __restrict__ bn1b,
           const float* __restrict__ m2w1, const float* __restrict__ m2b1,
           const float* __restrict__ m2w2, const float* __restrict__ m2b2,
           const float* __restrict__ bn2g, const float* __restrict__ bn2b,
           const float* __restrict__ m3pw, const float* __restrict__ m3pb,
           const float* __restrict__ m3w1, const float* __restrict__ m3b1,
           const float* __restrict__ m3w2, const float* __restrict__ m3b2,
           float* __restrict__ bns, unsigned* __restrict__ bar,
           float* __restrict__ T1, float* __restrict__ P1, float* __restrict__ Hm,
           float* __restrict__ T2, float* __restrict__ H2,
           float* __restrict__ T3, float* __restrict__ P3,
           float* __restrict__ hout){
  __shared__ float As[32][17];
  __shared__ __align__(16) float Ws[16][64];
  __shared__ float bnsc[512], bnsh[512];
  __shared__ float reds[16][64], reds2[16][64];
  unsigned* cnt = bar;
  unsigned* gen = bar + 1;
  const unsigned nblk = gridDim.x;

  // stage0: gfinal -> gout (d_out)
  for (int i = blockIdx.x*256 + threadIdx.x; i < 393216; i += nblk*256){
    int t = i >> 17, b = (i >> 8) & 511, c = i & 255;
    float d = den[t*B_ + b];
    float v = (d > 0.f) ? gacc[i]/d + bl[t*256+c] : 0.f;
    gout[i] = v + bout[t*256 + c];
  }
  gridbar(cnt, gen, nblk);

  // stage1: T1 = tanh(h0@m1w1+b1) [z=0], P1 = h0@m1pw+pb [z=1]; h0 gathered
  for (int job = blockIdx.x; job < 256; job += nblk){
    int z = job >> 7, r7 = job & 127;
    int row0 = (r7 >> 3)*32, col0 = (r7 & 7)*64;
    gemm_tile(nullptr, nullptr, ga, gout, nullptr, nullptr, nullptr,
              z ? m1pw : m1w1, z ? m1pb : m1b1, z ? P1 : T1, z ? 0 : 1,
              row0, col0, 832, 512, 1, 0, As, Ws, reds, reds2);
  }
  gridbar(cnt, gen, nblk);

  // stage2: Hm = T1@m1w2 + b2 + P1, bn1 stats
  for (int job = blockIdx.x; job < 128; job += nblk){
    int row0 = (job >> 3)*32, col0 = (job & 7)*64;
    gemm_tile(T1, P1, nullptr, nullptr, nullptr, nullptr, bns,
              m1w2, m1b2, Hm, 0, row0, col0, 512, 512, 0, 1, As, Ws, reds, reds2);
  }
  gridbar(cnt, gen, nblk);

  bn_precompute(bns, bn1g, bn1b, bnsc, bnsh);
  __syncthreads();

  // stage3: T2 = tanh( tanh(bn1(Hm)) @ m2w1 + b1 )
  for (int job = blockIdx.x; job < 128; job += nblk){
    int row0 = (job >> 3)*32, col0 = (job & 7)*64;
    gemm_tile(Hm, nullptr, nullptr, nullptr, bnsc, bnsh, nullptr,
              m2w1, m2b1, T2, 1, row0, col0, 512, 512, 2, 0, As, Ws, reds, reds2);
  }
  gridbar(cnt, gen, nblk);

  // stage4: H2 = T2@m2w2 + b2 + tanh(bn1(Hm)), bn2 stats (bn1 still in LDS)
  for (int job = blockIdx.x; job < 128; job += nblk){
    int row0 = (job >> 3)*32, col0 = (job & 7)*64;
    gemm_tile(T2, Hm, nullptr, nullptr, bnsc, bnsh, bns + 1024,
              m2w2, m2b2, H2, 0, row0, col0, 512, 512, 0, 2, As, Ws, reds, reds2);
  }
  gridbar(cnt, gen, nblk);

  bn_precompute(bns + 1024, bn2g, bn2b, bnsc, bnsh);
  __syncthreads();

  // stage5: A = tanh(bn2(H2)); T3 = tanh(A@m3w1+b1) [z=0], P3 = A@m3pw+pb [z=1]
  for (int job = blockIdx.x; job < 128; job += nblk){
    int z = job >> 6, r6 = job & 63;
    int row0 = (r6 >> 2)*32, col0 = (r6 & 3)*64;
    gemm_tile(H2, nullptr, nullptr, nullptr, bnsc, bnsh, nullptr,
              z ? m3pw : m3w1, z ? m3pb : m3b1, z ? P3 : T3, z ? 0 : 1,
              row0, col0, 512, 256, 2, 0, As, Ws, reds, reds2);
  }
  gridbar(cnt, gen, nblk);

  // stage6: hout = T3@m3w2 + b2 + P3
  for (int job = blockIdx.x; job < 64; job += nblk){
    int row0 = (job >> 2)*32, col0 = (job & 3)*64;
    gemm_tile(T3, P3, nullptr, nullptr, nullptr, nullptr, nullptr,
              m3w2, m3b2, hout, 0, row0, col0, 256, 256, 0, 1, As, Ws, reds, reds2);
  }
}

extern "C" void kernel_launch(void* const* d_in, const int* in_sizes, int n_in,
                              void* d_out, int out_size, void* d_ws, size_t ws_size,
                              hipStream_t stream){
  const float* x    = (const float*)d_in[0];
  const float* ga   = (const float*)d_in[1];
  const float* Wl   = (const float*)d_in[2];
  const float* bl   = (const float*)d_in[3];
  const float* Wr   = (const float*)d_in[4];
  const float* br   = (const float*)d_in[5];
  const float* att  = (const float*)d_in[6];
  const float* bout = (const float*)d_in[7];
  const float* gtok = (const float*)d_in[8];
  const float* m1pw = (const float*)d_in[9];
  const float* m1pb = (const float*)d_in[10];
  const float* m1w1 = (const float*)d_in[11];
  const float* m1b1 = (const float*)d_in[12];
  const float* m1w2 = (const float*)d_in[13];
  const float* m1b2 = (const float*)d_in[14];
  const float* bn1g = (const float*)d_in[15];
  const float* bn1b = (const float*)d_in[16];
  const float* m2w1 = (const float*)d_in[17];
  const float* m2b1 = (const float*)d_in[18];
  const float* m2w2 = (const float*)d_in[19];
  const float* m2b2 = (const float*)d_in[20];
  const float* bn2g = (const float*)d_in[21];
  const float* bn2b = (const float*)d_in[22];
  const float* m3pw = (const float*)d_in[23];
  const float* m3pb = (const float*)d_in[24];
  const float* m3w1 = (const float*)d_in[25];
  const float* m3b1 = (const float*)d_in[26];
  const float* m3w2 = (const float*)d_in[27];
  const float* m3b2 = (const float*)d_in[28];
  const int*   batch= (const int*)d_in[29];

  float* gout = (float*)d_out;              // [3][512][256]
  float* hout = (float*)d_out + 393216;     // [512][256]

  char* w = (char*)d_ws;
  __hip_bfloat16* wlt = (__hip_bfloat16*)(w + 0);   // 393216 B
  float*    cvec = (float*)(w + 393216);            // 3072 B
  float*    ebuf = (float*)(w + 396288);            // 2400000 B
  // zero region (398352 floats):
  float*    gacc = (float*)(w + 2796288);           // 1572864 B
  float*    den  = (float*)(w + 4369152);           // 6144 B
  unsigned* mkey = (unsigned*)(w + 4375296);        // 6144 B
  float*    bns  = (float*)(w + 4381440);           // 8192 B
  unsigned* bar  = (unsigned*)(w + 4389632);        // 64 B
  // head temps:
  float*    T1   = (float*)(w + 4389696);
  float*    P1   = (float*)(w + 5438272);
  float*    Hm   = (float*)(w + 6486848);
  float*    T2   = (float*)(w + 7535424);
  float*    H2   = (float*)(w + 8584000);
  float*    T3   = (float*)(w + 9632576);
  float*    P3   = (float*)(w + 10156864);

  kprep<<<435, 256, 0, stream>>>(Wl, wlt, Wr, bl, br, gtok, cvec, gacc);
  k1<<<512, 512, 0, stream>>>(x, wlt, cvec, att, batch, ebuf, mkey);
  kscan<<<dim3(782, 3), 256, 0, stream>>>(x, Wl, cvec, att, batch, ebuf, mkey, den, gacc);
  khead<<<256, 256, 0, stream>>>(ga, gacc, den, bl, bout, gout,
      m1pw, m1pb, m1w1, m1b1, m1w2, m1b2, bn1g, bn1b,
      m2w1, m2b1, m2w2, m2b2, bn2g, bn2b,
      m3pw, m3pb, m3w1, m3b1, m3w2, m3b2,
      bns, bar, T1, P1, Hm, T2, H2, T3, P3, hout);
}

// Round 6
// 532.748 us; speedup vs baseline: 1.8371x; 1.8371x over previous
//
#include <hip/hip_runtime.h>
#include <hip/hip_bf16.h>

typedef __bf16 bf16x8 __attribute__((ext_vector_type(8)));
typedef float  f32x4  __attribute__((ext_vector_type(4)));

#define T_   3
#define N_   200000
#define C_   256
#define B_   512
#define EPSb 1e-5f

__device__ __forceinline__ unsigned enc_f(float f){
  unsigned u = __float_as_uint(f);
  return (u & 0x80000000u) ? ~u : (u | 0x80000000u);
}
__device__ __forceinline__ float dec_f(unsigned k){
  unsigned u = (k & 0x80000000u) ? (k ^ 0x80000000u) : ~k;
  return __uint_as_float(u);
}
// fast tanh: exact at +-inf, ~1e-6 rel err, all VALU-fast ops
__device__ __forceinline__ float ftanh(float x){
  float e = __expf(2.0f*x);
  return 1.0f - 2.0f/(e + 1.0f);
}

// raw barrier WITHOUT vmcnt drain (lets prefetch global loads stay in flight)
__device__ __forceinline__ void barrier_nodrain(){
  __builtin_amdgcn_sched_barrier(0);
  asm volatile("s_waitcnt lgkmcnt(0)" ::: "memory");
  __builtin_amdgcn_s_barrier();
  __builtin_amdgcn_sched_barrier(0);
}

// ---------------- prep: Wl transpose->bf16, cvec, zero-fill (one kernel)
__global__ void kprep(const float* __restrict__ Wl, __hip_bfloat16* __restrict__ wlt,
                      const float* __restrict__ Wr, const float* __restrict__ bl,
                      const float* __restrict__ br, const float* __restrict__ gtok,
                      float* __restrict__ cvec, float* __restrict__ zr){
  __shared__ float tile[64][65];
  __shared__ float gt[256];
  int blk = blockIdx.x, tid = threadIdx.x;
  if (blk < 48){
    int t = blk / 16, rem = blk % 16;
    int k0 = (rem >> 2)*64, c0 = (rem & 3)*64;
    int lc = tid & 63, lr0 = tid >> 6;
    #pragma unroll
    for (int q = 0; q < 16; q++){
      int lr = lr0*16 + q;
      tile[lr][lc] = Wl[t*65536 + (k0+lr)*256 + (c0+lc)];
    }
    __syncthreads();
    #pragma unroll
    for (int q = 0; q < 16; q++){
      int lr = lr0*16 + q;
      wlt[t*65536 + (c0+lr)*256 + (k0+lc)] = __float2bfloat16(tile[lc][lr]);
    }
  } else if (blk < 51){
    int t = blk - 48, c = tid;
    gt[tid] = gtok[t*256 + tid];
    __syncthreads();
    const float* wr = Wr + t*65536 + c;
    float a0=0.f,a1=0.f,a2=0.f,a3=0.f;
    #pragma unroll 2
    for (int k = 0; k < 256; k += 4){
      a0 += gt[k]  *wr[k*256];
      a1 += gt[k+1]*wr[(k+1)*256];
      a2 += gt[k+2]*wr[(k+2)*256];
      a3 += gt[k+3]*wr[(k+3)*256];
    }
    cvec[t*256 + c] = a0+a1+a2+a3 + bl[t*256+c] + br[t*256+c];
  } else {
    // zero region: gacc(393216)+den(1536)+mkey(1536)+bns(2048) floats
    for (int i = (blk-51)*256 + tid; i < 398336; i += (gridDim.x-51)*256) zr[i] = 0.f;
  }
}

// ---------------- big pass (contiguous ranges): e_approx = att.lrelu(x@Wl+cvec)
__global__ __launch_bounds__(512, 2)
void k1(const float* __restrict__ x, const __hip_bfloat16* __restrict__ wlt,
        const float* __restrict__ cvec, const float* __restrict__ att,
        const int* __restrict__ batch, float* __restrict__ e_out,
        unsigned* __restrict__ mkey){
  __shared__ __align__(16) __hip_bfloat16 Abuf[64][256];
  __shared__ float elds[4][64];
  const int tid = threadIdx.x;
  const int w = tid >> 6, l = tid & 63;
  const int wcol = w & 3, wrow = w >> 2;
  const int l15 = l & 15, l4 = l >> 4;
  const int srow = tid >> 3;
  const int sc   = tid & 7;
  const int sx   = srow & 7;

  bf16x8 bfr[8][4];
  float cv[4], at[4];
  int cur_t = -1;

  const int bid = blockIdx.x;
  const int nt = 18 + (bid < 159 ? 1 : 0);
  const int g0 = bid*18 + (bid < 159 ? bid : 159);

  f32x4 rg[8];
  {
    int t = g0 / 3125, tile = g0 % 3125;
    const float* xrow = x + (size_t)t*N_*256 + (size_t)(tile*64 + srow)*256;
    #pragma unroll
    for (int q = 0; q < 4; q++){
      int cs = (q*8 + sc) ^ sx;
      rg[2*q]   = *(const f32x4*)(xrow + cs*8);
      rg[2*q+1] = *(const f32x4*)(xrow + cs*8 + 4);
    }
  }

  for (int it = 0; it < nt; ++it){
    const int gt = g0 + it;
    const int t = gt / 3125, tile = gt % 3125;
    if (t != cur_t){
      cur_t = t;
      const __hip_bfloat16* WT = wlt + t*65536;
      #pragma unroll
      for (int fn = 0; fn < 4; fn++){
        int col = wcol*64 + fn*16 + l15;
        cv[fn] = cvec[t*256 + col];
        at[fn] = att[t*256 + col];
        #pragma unroll
        for (int ks = 0; ks < 8; ks++)
          bfr[ks][fn] = *(const bf16x8*)(WT + col*256 + ks*32 + l4*8);
      }
    }
    // stage rg -> LDS (swizzled slots)
    #pragma unroll
    for (int q = 0; q < 4; q++){
      bf16x8 v;
      #pragma unroll
      for (int j = 0; j < 4; j++){ v[j] = (__bf16)rg[2*q][j]; v[4+j] = (__bf16)rg[2*q+1][j]; }
      *(bf16x8*)(&Abuf[srow][(q*8 + sc)*8]) = v;
    }
    // prefetch next tile (stays in flight across the raw barrier)
    if (it + 1 < nt){
      int gn = gt + 1;
      int tn = gn / 3125, tilen = gn % 3125;
      const float* xrow = x + (size_t)tn*N_*256 + (size_t)(tilen*64 + srow)*256;
      #pragma unroll
      for (int q = 0; q < 4; q++){
        int cs = (q*8 + sc) ^ sx;
        rg[2*q]   = *(const f32x4*)(xrow + cs*8);
        rg[2*q+1] = *(const f32x4*)(xrow + cs*8 + 4);
      }
    }
    barrier_nodrain();

    f32x4 acc[2][4];
    #pragma unroll
    for (int fm = 0; fm < 2; fm++)
      #pragma unroll
      for (int fn = 0; fn < 4; fn++)
        acc[fm][fn] = (f32x4){0.f,0.f,0.f,0.f};

    #pragma unroll
    for (int ks = 0; ks < 8; ks++){
      bf16x8 a8[2];
      #pragma unroll
      for (int fm = 0; fm < 2; fm++){
        int row  = wrow*32 + fm*16 + l15;
        int slot = (ks*4 + l4) ^ (row & 7);
        a8[fm] = *(const bf16x8*)(&Abuf[row][slot*8]);
      }
      #pragma unroll
      for (int fm = 0; fm < 2; fm++)
        #pragma unroll
        for (int fn = 0; fn < 4; fn++)
          acc[fm][fn] = __builtin_amdgcn_mfma_f32_16x16x32_bf16(a8[fm], bfr[ks][fn], acc[fm][fn], 0, 0, 0);
    }

    #pragma unroll
    for (int fm = 0; fm < 2; fm++){
      #pragma unroll
      for (int r = 0; r < 4; r++){
        float v = 0.f;
        #pragma unroll
        for (int fn = 0; fn < 4; fn++){
          float xv = acc[fm][fn][r] + cv[fn];
          xv = (xv > 0.f) ? xv : 0.2f*xv;
          v += xv * at[fn];
        }
        v += __shfl_xor(v, 1);
        v += __shfl_xor(v, 2);
        v += __shfl_xor(v, 4);
        v += __shfl_xor(v, 8);
        if (l15 == 0) elds[wcol][wrow*32 + fm*16 + l4*4 + r] = v;
      }
    }
    barrier_nodrain();

    if (tid < 64){
      float ef = elds[0][tid] + elds[1][tid] + elds[2][tid] + elds[3][tid];
      int n = tile*64 + tid;
      e_out[t*N_ + n] = ef;
      int b = batch[t*N_ + n];
      float m = ef;
      #pragma unroll
      for (int off = 1; off < 64; off <<= 1){
        float up = __shfl_up(m, off);
        int   bu = __shfl_up(b, off);
        if (tid >= off && bu == b) m = fmaxf(m, up);
      }
      int bnx = __shfl_down(b, 1);
      if (tid == 63 || b != bnx) atomicMax(&mkey[t*B_ + b], enc_f(m));
    }
  }
}

// ---------------- fused select+candidate pass: threshold scan, then exact
// fp32 xl + e + den + gacc for hits (softmax shift uses approx max: exact)
__global__ void kscan(const float* __restrict__ x, const float* __restrict__ Wl,
                      const float* __restrict__ cvec, const float* __restrict__ att,
                      const int* __restrict__ batch, const float* __restrict__ e,
                      const unsigned* __restrict__ mkey,
                      float* __restrict__ den, float* __restrict__ gacc){
  __shared__ float xs[256];
  __shared__ float red[4];
  __shared__ float ebc;
  __shared__ int hits[256];
  __shared__ int nh;
  int t = blockIdx.y;
  int tid = threadIdx.x;
  int n0 = blockIdx.x*256;
  int n = n0 + tid;
  if (tid == 0) nh = 0;
  __syncthreads();
  if (n < N_){
    float ev = e[t*N_ + n];
    int b = batch[t*N_ + n];
    float m = dec_f(mkey[t*B_ + b]);
    if (ev >= m - 30.0f){ int p = atomicAdd(&nh, 1); hits[p] = tid; }
  }
  __syncthreads();
  int cnum = nh;
  for (int i = 0; i < cnum; i++){
    int hn = n0 + hits[i];
    xs[tid] = x[(size_t)t*N_*256 + (size_t)hn*256 + tid];
    __syncthreads();
    const float* wp = Wl + t*65536 + tid;
    float a0 = 0.f, a1 = 0.f;
    #pragma unroll 8
    for (int k = 0; k < 256; k += 2){
      a0 += xs[k]   * wp[k*256];
      a1 += xs[k+1] * wp[(k+1)*256];
    }
    float xl = a0 + a1;
    float xv = xl + cvec[t*256 + tid];
    xv = (xv > 0.f) ? xv : 0.2f*xv;
    float term = xv * att[t*256 + tid];
    #pragma unroll
    for (int off = 1; off < 64; off <<= 1) term += __shfl_xor(term, off);
    if ((tid & 63) == 0) red[tid >> 6] = term;
    __syncthreads();
    if (tid == 0) ebc = red[0] + red[1] + red[2] + red[3];
    __syncthreads();
    int b = batch[t*N_ + hn];
    float m = dec_f(mkey[t*B_ + b]);
    float wv = expf(ebc - m);
    if (tid == 0) atomicAdd(&den[t*B_ + b], wv);
    atomicAdd(&gacc[t*131072 + b*256 + tid], wv * xl);
    __syncthreads();
  }
}

// ---------------- finalize g: gout = gacc/den + bl + bias_out
__global__ void kgfinal(const float* __restrict__ gacc, const float* __restrict__ den,
                        const float* __restrict__ bl, const float* __restrict__ bout,
                        float* __restrict__ gout){
  int i = blockIdx.x*256 + threadIdx.x;
  if (i >= 393216) return;
  int t = i >> 17, b = (i >> 8) & 511, c = i & 255;
  float d = den[t*B_ + b];
  float v = (d > 0.f) ? gacc[i]/d + bl[t*256+c] : 0.f;
  gout[i] = v + bout[t*256 + c];
}

// ---------------- head GEMM: out = [tanh](Aeff@W + bias [+ addeff]), dual-z,
// Aeff: 0=plain, 1=concat-gather(ga,gfin), 2=tanh(bn(A)); addeff: 0/1 plain/2 bn
__global__ __launch_bounds__(256)
void kgemm2(const float* __restrict__ A, const float* __restrict__ addsrc,
            const float* __restrict__ ga, const float* __restrict__ gfin,
            const float* __restrict__ bnsums, const float* __restrict__ bng,
            const float* __restrict__ bnb, float* __restrict__ stats,
            const float* __restrict__ W0, const float* __restrict__ bias0,
            float* __restrict__ out0, int tanh0,
            const float* __restrict__ W1, const float* __restrict__ bias1,
            float* __restrict__ out1, int tanh1,
            int M, int N, int K, int aMode, int addMode){
  __shared__ float As[32][17];
  __shared__ __align__(16) float Ws[16][64];
  __shared__ float bnsc[512], bnsh[512];
  __shared__ float reds[16][64], reds2[16][64];

  const float* W = W0; const float* bias = bias0; float* out = out0; int dotanh = tanh0;
  if (blockIdx.z){ W = W1; bias = bias1; out = out1; dotanh = tanh1; }

  int tid = threadIdx.x;
  int tx = tid & 15, ty = tid >> 4;
  int row0 = blockIdx.y * 32, col0 = blockIdx.x * 64;

  if (aMode == 2 || addMode == 2){
    #pragma unroll
    for (int q = 0; q < 2; q++){
      int k = q*256 + tid;
      float mu = bnsums[k] * (1.f/512.f);
      float var = bnsums[512+k] * (1.f/512.f) - mu*mu;
      float sc = bng[k] * __frsqrt_rn(var + EPSb);
      bnsc[k] = sc;
      bnsh[k] = bnb[k] - mu*sc;
    }
    __syncthreads();
  }

  float acc[2][4] = {};
  for (int k0 = 0; k0 < K; k0 += 16){
    #pragma unroll
    for (int q = 0; q < 2; q++){
      int idx = tid*2 + q;
      int r = idx >> 4, kk = idx & 15;
      int kg = k0 + kk;
      float v;
      if (aMode == 0)      v = A[(size_t)(row0+r)*K + kg];
      else if (aMode == 1) v = (kg < 64) ? ga[(row0+r)*64 + kg]
                               : gfin[((kg-64) >> 8)*131072 + (row0+r)*256 + ((kg-64)&255)];
      else                 v = ftanh(A[(row0+r)*512 + kg]*bnsc[kg] + bnsh[kg]);
      As[r][kk] = v;
    }
    {
      int kr = tid >> 4, cc = (tid & 15)*4;
      *(f32x4*)&Ws[kr][cc] = *(const f32x4*)&W[(size_t)(k0+kr)*N + col0 + cc];
    }
    __syncthreads();
    #pragma unroll
    for (int kk = 0; kk < 16; kk++){
      float a0 = As[ty][kk], a1 = As[ty+16][kk];
      f32x4 wv = *(const f32x4*)&Ws[kk][tx*4];
      #pragma unroll
      for (int j = 0; j < 4; j++){
        acc[0][j] += a0*wv[j];
        acc[1][j] += a1*wv[j];
      }
    }
    __syncthreads();
  }

  float vout[2][4];
  #pragma unroll
  for (int i2 = 0; i2 < 2; i2++){
    int row = row0 + ty + i2*16;
    #pragma unroll
    for (int j = 0; j < 4; j++){
      int col = col0 + tx*4 + j;
      float v = acc[i2][j] + bias[col];
      if (addMode == 1) v += addsrc[(size_t)row*N + col];
      else if (addMode == 2) v += ftanh(addsrc[row*512 + col]*bnsc[col] + bnsh[col]);
      if (dotanh) v = ftanh(v);
      out[(size_t)row*N + col] = v;
      vout[i2][j] = v;
    }
  }

  if (stats){
    __syncthreads();
    #pragma unroll
    for (int j = 0; j < 4; j++){
      reds[ty][tx*4+j]  = vout[0][j] + vout[1][j];
      reds2[ty][tx*4+j] = vout[0][j]*vout[0][j] + vout[1][j]*vout[1][j];
    }
    __syncthreads();
    if (tid < 128){
      int col = tid & 63, which = tid >> 6;
      const float (*src)[64] = which ? reds2 : reds;
      float s = 0.f;
      #pragma unroll
      for (int r = 0; r < 16; r++) s += src[r][col];
      atomicAdd(&stats[which*512 + col0 + col], s);
    }
  }
}

extern "C" void kernel_launch(void* const* d_in, const int* in_sizes, int n_in,
                              void* d_out, int out_size, void* d_ws, size_t ws_size,
                              hipStream_t stream){
  const float* x    = (const float*)d_in[0];
  const float* ga   = (const float*)d_in[1];
  const float* Wl   = (const float*)d_in[2];
  const float* bl   = (const float*)d_in[3];
  const float* Wr   = (const float*)d_in[4];
  const float* br   = (const float*)d_in[5];
  const float* att  = (const float*)d_in[6];
  const float* bout = (const float*)d_in[7];
  const float* gtok = (const float*)d_in[8];
  const float* m1pw = (const float*)d_in[9];
  const float* m1pb = (const float*)d_in[10];
  const float* m1w1 = (const float*)d_in[11];
  const float* m1b1 = (const float*)d_in[12];
  const float* m1w2 = (const float*)d_in[13];
  const float* m1b2 = (const float*)d_in[14];
  const float* bn1g = (const float*)d_in[15];
  const float* bn1b = (const float*)d_in[16];
  const float* m2w1 = (const float*)d_in[17];
  const float* m2b1 = (const float*)d_in[18];
  const float* m2w2 = (const float*)d_in[19];
  const float* m2b2 = (const float*)d_in[20];
  const float* bn2g = (const float*)d_in[21];
  const float* bn2b = (const float*)d_in[22];
  const float* m3pw = (const float*)d_in[23];
  const float* m3pb = (const float*)d_in[24];
  const float* m3w1 = (const float*)d_in[25];
  const float* m3b1 = (const float*)d_in[26];
  const float* m3w2 = (const float*)d_in[27];
  const float* m3b2 = (const float*)d_in[28];
  const int*   batch= (const int*)d_in[29];

  float* gout = (float*)d_out;              // [3][512][256]
  float* hout = (float*)d_out + 393216;     // [512][256]

  char* w = (char*)d_ws;
  __hip_bfloat16* wlt = (__hip_bfloat16*)(w + 0);   // 393216 B
  float*    cvec = (float*)(w + 393216);            // 3072 B
  float*    ebuf = (float*)(w + 396288);            // 2400000 B
  // zero region (398336 floats):
  float*    gacc = (float*)(w + 2796288);           // 1572864 B
  float*    den  = (float*)(w + 4369152);           // 6144 B
  unsigned* mkey = (unsigned*)(w + 4375296);        // 6144 B
  float*    bns  = (float*)(w + 4381440);           // 8192 B
  // head temps:
  float*    T1   = (float*)(w + 4389632);
  float*    P1   = (float*)(w + 5438208);
  float*    Hm   = (float*)(w + 6486784);
  float*    T2   = (float*)(w + 7535360);
  float*    H2   = (float*)(w + 8583936);
  float*    T3   = (float*)(w + 9632512);
  float*    P3   = (float*)(w + 10156800);

  kprep<<<435, 256, 0, stream>>>(Wl, wlt, Wr, bl, br, gtok, cvec, gacc);
  k1<<<512, 512, 0, stream>>>(x, wlt, cvec, att, batch, ebuf, mkey);
  kscan<<<dim3(782, 3), 256, 0, stream>>>(x, Wl, cvec, att, batch, ebuf, mkey, den, gacc);
  kgfinal<<<1536, 256, 0, stream>>>(gacc, den, bl, bout, gout);
  // stage 1: T1 = tanh(h0@m1w1+b1), P1 = h0@m1pw+pb  (gather A)
  kgemm2<<<dim3(8,16,2), 256, 0, stream>>>(nullptr, nullptr, ga, gout,
      nullptr, nullptr, nullptr, nullptr,
      m1w1, m1b1, T1, 1, m1pw, m1pb, P1, 0, 512, 512, 832, 1, 0);
  // Hm = T1@m1w2 + b2 + P1, bn1 stats fused
  kgemm2<<<dim3(8,16,1), 256, 0, stream>>>(T1, P1, nullptr, nullptr,
      nullptr, nullptr, nullptr, bns,
      m1w2, m1b2, Hm, 0, nullptr, nullptr, nullptr, 0, 512, 512, 512, 0, 1);
  // T2 = tanh( tanh(bn1(Hm)) @ m2w1 + b1 )
  kgemm2<<<dim3(8,16,1), 256, 0, stream>>>(Hm, nullptr, nullptr, nullptr,
      bns, bn1g, bn1b, nullptr,
      m2w1, m2b1, T2, 1, nullptr, nullptr, nullptr, 0, 512, 512, 512, 2, 0);
  // H2 = T2@m2w2 + b2 + tanh(bn1(Hm)), bn2 stats fused
  kgemm2<<<dim3(8,16,1), 256, 0, stream>>>(T2, Hm, nullptr, nullptr,
      bns, bn1g, bn1b, bns + 1024,
      m2w2, m2b2, H2, 0, nullptr, nullptr, nullptr, 0, 512, 512, 512, 0, 2);
  // stage 3: A = tanh(bn2(H2)); T3 = tanh(A@m3w1+b1), P3 = A@m3pw+pb
  kgemm2<<<dim3(4,16,2), 256, 0, stream>>>(H2, nullptr, nullptr, nullptr,
      bns + 1024, bn2g, bn2b, nullptr,
      m3w1, m3b1, T3, 1, m3pw, m3pb, P3, 0, 512, 256, 512, 2, 0);
  // hout = T3@m3w2 + b2 + P3
  kgemm2<<<dim3(4,16,1), 256, 0, stream>>>(T3, P3, nullptr, nullptr,
      nullptr, nullptr, nullptr, nullptr,
      m3w2, m3b2, hout, 0, nullptr, nullptr, nullptr, 0, 512, 256, 256, 0, 1);
}

// Round 8
// 393.353 us; speedup vs baseline: 2.4881x; 1.3544x over previous
//
#include <hip/hip_runtime.h>
#include <hip/hip_bf16.h>

typedef __bf16 bf16x8 __attribute__((ext_vector_type(8)));
typedef float  f32x4  __attribute__((ext_vector_type(4)));

#define T_   3
#define N_   200000
#define C_   256
#define B_   512
#define EPSb 1e-5f

__device__ __forceinline__ unsigned enc_f(float f){
  unsigned u = __float_as_uint(f);
  return (u & 0x80000000u) ? ~u : (u | 0x80000000u);
}
__device__ __forceinline__ float dec_f(unsigned k){
  unsigned u = (k & 0x80000000u) ? (k ^ 0x80000000u) : ~k;
  return __uint_as_float(u);
}
// fast tanh: exact at +-inf, ~1e-6 rel err
__device__ __forceinline__ float ftanh(float x){
  float e = __expf(2.0f*x);
  return 1.0f - 2.0f/(e + 1.0f);
}

// raw barrier WITHOUT vmcnt drain (prefetch global loads stay in flight)
__device__ __forceinline__ void barrier_nodrain(){
  __builtin_amdgcn_sched_barrier(0);
  asm volatile("s_waitcnt lgkmcnt(0)" ::: "memory");
  __builtin_amdgcn_s_barrier();
  __builtin_amdgcn_sched_barrier(0);
}

// ---------------- prep: Wl transpose->bf16, cvec, zero-fill (one kernel)
__global__ void kprep(const float* __restrict__ Wl, __hip_bfloat16* __restrict__ wlt,
                      const float* __restrict__ Wr, const float* __restrict__ bl,
                      const float* __restrict__ br, const float* __restrict__ gtok,
                      float* __restrict__ cvec, float* __restrict__ zr){
  __shared__ float tile[64][65];
  __shared__ float gt[256];
  int blk = blockIdx.x, tid = threadIdx.x;
  if (blk < 48){
    int t = blk / 16, rem = blk % 16;
    int k0 = (rem >> 2)*64, c0 = (rem & 3)*64;
    int lc = tid & 63, lr0 = tid >> 6;
    #pragma unroll
    for (int q = 0; q < 16; q++){
      int lr = lr0*16 + q;
      tile[lr][lc] = Wl[t*65536 + (k0+lr)*256 + (c0+lc)];
    }
    __syncthreads();
    #pragma unroll
    for (int q = 0; q < 16; q++){
      int lr = lr0*16 + q;
      wlt[t*65536 + (c0+lr)*256 + (k0+lc)] = __float2bfloat16(tile[lc][lr]);
    }
  } else if (blk < 51){
    int t = blk - 48, c = tid;
    gt[tid] = gtok[t*256 + tid];
    __syncthreads();
    const float* wr = Wr + t*65536 + c;
    float a0=0.f,a1=0.f,a2=0.f,a3=0.f;
    #pragma unroll 2
    for (int k = 0; k < 256; k += 4){
      a0 += gt[k]  *wr[k*256];
      a1 += gt[k+1]*wr[(k+1)*256];
      a2 += gt[k+2]*wr[(k+2)*256];
      a3 += gt[k+3]*wr[(k+3)*256];
    }
    cvec[t*256 + c] = a0+a1+a2+a3 + bl[t*256+c] + br[t*256+c];
  } else {
    // zero region: gacc(393216)+den(1536)+mkey(1536)+bns(2048) floats
    for (int i = (blk-51)*256 + tid; i < 398336; i += (gridDim.x-51)*256) zr[i] = 0.f;
  }
}

// ---------------- big pass (contiguous ranges): e_approx = att.lrelu(x@Wl+cvec)
__global__ __launch_bounds__(512, 2)
void k1(const float* __restrict__ x, const __hip_bfloat16* __restrict__ wlt,
        const float* __restrict__ cvec, const float* __restrict__ att,
        const int* __restrict__ batch, float* __restrict__ e_out,
        unsigned* __restrict__ mkey){
  __shared__ __align__(16) __hip_bfloat16 Abuf[64][256];
  __shared__ float elds[4][64];
  const int tid = threadIdx.x;
  const int w = tid >> 6, l = tid & 63;
  const int wcol = w & 3, wrow = w >> 2;
  const int l15 = l & 15, l4 = l >> 4;
  const int srow = tid >> 3;
  const int sc   = tid & 7;
  const int sx   = srow & 7;

  bf16x8 bfr[8][4];
  float cv[4], at[4];
  int cur_t = -1;

  const int bid = blockIdx.x;
  const int nt = 18 + (bid < 159 ? 1 : 0);
  const int g0 = bid*18 + (bid < 159 ? bid : 159);

  f32x4 rg[8];
  {
    int t = g0 / 3125, tile = g0 % 3125;
    const float* xrow = x + (size_t)t*N_*256 + (size_t)(tile*64 + srow)*256;
    #pragma unroll
    for (int q = 0; q < 4; q++){
      int cs = (q*8 + sc) ^ sx;
      rg[2*q]   = *(const f32x4*)(xrow + cs*8);
      rg[2*q+1] = *(const f32x4*)(xrow + cs*8 + 4);
    }
  }

  for (int it = 0; it < nt; ++it){
    const int gt = g0 + it;
    const int t = gt / 3125, tile = gt % 3125;
    if (t != cur_t){
      cur_t = t;
      const __hip_bfloat16* WT = wlt + t*65536;
      #pragma unroll
      for (int fn = 0; fn < 4; fn++){
        int col = wcol*64 + fn*16 + l15;
        cv[fn] = cvec[t*256 + col];
        at[fn] = att[t*256 + col];
        #pragma unroll
        for (int ks = 0; ks < 8; ks++)
          bfr[ks][fn] = *(const bf16x8*)(WT + col*256 + ks*32 + l4*8);
      }
    }
    #pragma unroll
    for (int q = 0; q < 4; q++){
      bf16x8 v;
      #pragma unroll
      for (int j = 0; j < 4; j++){ v[j] = (__bf16)rg[2*q][j]; v[4+j] = (__bf16)rg[2*q+1][j]; }
      *(bf16x8*)(&Abuf[srow][(q*8 + sc)*8]) = v;
    }
    if (it + 1 < nt){
      int gn = gt + 1;
      int tn = gn / 3125, tilen = gn % 3125;
      const float* xrow = x + (size_t)tn*N_*256 + (size_t)(tilen*64 + srow)*256;
      #pragma unroll
      for (int q = 0; q < 4; q++){
        int cs = (q*8 + sc) ^ sx;
        rg[2*q]   = *(const f32x4*)(xrow + cs*8);
        rg[2*q+1] = *(const f32x4*)(xrow + cs*8 + 4);
      }
    }
    barrier_nodrain();

    f32x4 acc[2][4];
    #pragma unroll
    for (int fm = 0; fm < 2; fm++)
      #pragma unroll
      for (int fn = 0; fn < 4; fn++)
        acc[fm][fn] = (f32x4){0.f,0.f,0.f,0.f};

    #pragma unroll
    for (int ks = 0; ks < 8; ks++){
      bf16x8 a8[2];
      #pragma unroll
      for (int fm = 0; fm < 2; fm++){
        int row  = wrow*32 + fm*16 + l15;
        int slot = (ks*4 + l4) ^ (row & 7);
        a8[fm] = *(const bf16x8*)(&Abuf[row][slot*8]);
      }
      #pragma unroll
      for (int fm = 0; fm < 2; fm++)
        #pragma unroll
        for (int fn = 0; fn < 4; fn++)
          acc[fm][fn] = __builtin_amdgcn_mfma_f32_16x16x32_bf16(a8[fm], bfr[ks][fn], acc[fm][fn], 0, 0, 0);
    }

    #pragma unroll
    for (int fm = 0; fm < 2; fm++){
      #pragma unroll
      for (int r = 0; r < 4; r++){
        float v = 0.f;
        #pragma unroll
        for (int fn = 0; fn < 4; fn++){
          float xv = acc[fm][fn][r] + cv[fn];
          xv = (xv > 0.f) ? xv : 0.2f*xv;
          v += xv * at[fn];
        }
        v += __shfl_xor(v, 1);
        v += __shfl_xor(v, 2);
        v += __shfl_xor(v, 4);
        v += __shfl_xor(v, 8);
        if (l15 == 0) elds[wcol][wrow*32 + fm*16 + l4*4 + r] = v;
      }
    }
    barrier_nodrain();

    if (tid < 64){
      float ef = elds[0][tid] + elds[1][tid] + elds[2][tid] + elds[3][tid];
      int n = tile*64 + tid;
      e_out[t*N_ + n] = ef;
      int b = batch[t*N_ + n];
      float m = ef;
      #pragma unroll
      for (int off = 1; off < 64; off <<= 1){
        float up = __shfl_up(m, off);
        int   bu = __shfl_up(b, off);
        if (tid >= off && bu == b) m = fmaxf(m, up);
      }
      int bnx = __shfl_down(b, 1);
      if (tid == 63 || b != bnx) atomicMax(&mkey[t*B_ + b], enc_f(m));
    }
  }
}

// ---------------- fused select+candidate pass
__global__ void kscan(const float* __restrict__ x, const float* __restrict__ Wl,
                      const float* __restrict__ cvec, const float* __restrict__ att,
                      const int* __restrict__ batch, const float* __restrict__ e,
                      const unsigned* __restrict__ mkey,
                      float* __restrict__ den, float* __restrict__ gacc){
  __shared__ float xs[256];
  __shared__ float red[4];
  __shared__ float ebc;
  __shared__ int hits[256];
  __shared__ int nh;
  int t = blockIdx.y;
  int tid = threadIdx.x;
  int n0 = blockIdx.x*256;
  int n = n0 + tid;
  if (tid == 0) nh = 0;
  __syncthreads();
  if (n < N_){
    float ev = e[t*N_ + n];
    int b = batch[t*N_ + n];
    float m = dec_f(mkey[t*B_ + b]);
    if (ev >= m - 30.0f){ int p = atomicAdd(&nh, 1); hits[p] = tid; }
  }
  __syncthreads();
  int cnum = nh;
  for (int i = 0; i < cnum; i++){
    int hn = n0 + hits[i];
    xs[tid] = x[(size_t)t*N_*256 + (size_t)hn*256 + tid];
    __syncthreads();
    const float* wp = Wl + t*65536 + tid;
    float a0 = 0.f, a1 = 0.f;
    #pragma unroll 8
    for (int k = 0; k < 256; k += 2){
      a0 += xs[k]   * wp[k*256];
      a1 += xs[k+1] * wp[(k+1)*256];
    }
    float xl = a0 + a1;
    float xv = xl + cvec[t*256 + tid];
    xv = (xv > 0.f) ? xv : 0.2f*xv;
    float term = xv * att[t*256 + tid];
    #pragma unroll
    for (int off = 1; off < 64; off <<= 1) term += __shfl_xor(term, off);
    if ((tid & 63) == 0) red[tid >> 6] = term;
    __syncthreads();
    if (tid == 0) ebc = red[0] + red[1] + red[2] + red[3];
    __syncthreads();
    int b = batch[t*N_ + hn];
    float m = dec_f(mkey[t*B_ + b]);
    float wv = expf(ebc - m);
    if (tid == 0) atomicAdd(&den[t*B_ + b], wv);
    atomicAdd(&gacc[t*131072 + b*256 + tid], wv * xl);
    __syncthreads();
  }
}

// ---------------- finalize g
__global__ void kgfinal(const float* __restrict__ gacc, const float* __restrict__ den,
                        const float* __restrict__ bl, const float* __restrict__ bout,
                        float* __restrict__ gout){
  int i = blockIdx.x*256 + threadIdx.x;
  if (i >= 393216) return;
  int t = i >> 17, b = (i >> 8) & 511, c = i & 255;
  float d = den[t*B_ + b];
  float v = (d > 0.f) ? gacc[i]/d + bl[t*256+c] : 0.f;
  gout[i] = v + bout[t*256 + c];
}

// ---------------- staging loads for kmfma (A: 8 k's of one row; W: one col, 8 k's)
__device__ __forceinline__ void load_stage(const float* __restrict__ A,
    const float* __restrict__ W, const float* __restrict__ ga,
    const float* __restrict__ gfin, int aMode, int K, int N,
    int row0, int col0, int arow, int akq, int wcol, int wkg, int s,
    float* av, float* wv){
  int k0 = s << 5;
  int kg = k0 + akq*8;
  const float* p;
  if (aMode == 0)      p = A + (size_t)(row0+arow)*K + kg;
  else if (aMode == 1) p = (kg < 64) ? ga + (size_t)(row0+arow)*64 + kg
                         : gfin + (size_t)((kg-64) >> 8)*131072 + (size_t)(row0+arow)*256 + ((kg-64) & 255);
  else                 p = A + (size_t)(row0+arow)*512 + kg;
  f32x4 v0 = *(const f32x4*)p;
  f32x4 v1 = *(const f32x4*)(p + 4);
  av[0]=v0[0]; av[1]=v0[1]; av[2]=v0[2]; av[3]=v0[3];
  av[4]=v1[0]; av[5]=v1[1]; av[6]=v1[2]; av[7]=v1[3];
  const float* q = W + (size_t)(k0 + wkg*8)*N + col0 + wcol;
  #pragma unroll
  for (int j = 0; j < 8; j++) wv[j] = q[(size_t)j*N];
}

// ---------------- MFMA head GEMM, split-bf16 error compensation:
// each operand v = hi + lo (bf16 pair); acc += hi*hi + hi*lo + lo*hi.
// Dropped lo*lo term: rel ~2^-18 -> fp32-equivalent for this graph.
// aMode: 0 plain A[M][K]; 1 gather(ga,gfin); 2 tanh(bn(A)) (A is 512-wide)
// addMode: 0 none; 1 +addsrc; 2 +tanh(bn(addsrc)) (addsrc 512-wide)
__global__ __launch_bounds__(256)
void kmfma(const float* __restrict__ A, const float* __restrict__ addsrc,
           const float* __restrict__ ga, const float* __restrict__ gfin,
           const float* __restrict__ bnsums, const float* __restrict__ bng,
           const float* __restrict__ bnb, float* __restrict__ stats,
           const float* __restrict__ W0, const float* __restrict__ bias0,
           float* __restrict__ out0, int tanh0,
           const float* __restrict__ W1, const float* __restrict__ bias1,
           float* __restrict__ out1, int tanh1,
           int N, int K, int aMode, int addMode){
  __shared__ __align__(16) __bf16 As[2][64][40];   // [hi/lo][row][k]
  __shared__ __align__(16) __bf16 Ws[2][64][40];   // [hi/lo][col][k]
  __shared__ float bnsc[512], bnsh[512];
  __shared__ float reds[16][64];

  const float* W = W0; const float* bias = bias0; float* out = out0; int dotanh = tanh0;
  if (blockIdx.z){ W = W1; bias = bias1; out = out1; dotanh = tanh1; }

  const int tid = threadIdx.x;
  const int w = tid >> 6, l = tid & 63;
  const int l15 = l & 15, l4 = l >> 4;
  const int row0 = blockIdx.y*64, col0 = blockIdx.x*64;
  const int arow = tid >> 2, akq = tid & 3;   // A stage: row 0..63, k-chunk 0..3
  const int wcol = tid & 63, wkg = tid >> 6;  // W stage: col 0..63, k-chunk 0..3

  if (aMode == 2 || addMode == 2){
    #pragma unroll
    for (int q = 0; q < 2; q++){
      int k = q*256 + tid;
      float mu = bnsums[k] * (1.f/512.f);
      float var = bnsums[512+k] * (1.f/512.f) - mu*mu;
      float sc = bng[k] * __frsqrt_rn(var + EPSb);
      bnsc[k] = sc;
      bnsh[k] = bnb[k] - mu*sc;
    }
    __syncthreads();
  }

  f32x4 acc[4];
  #pragma unroll
  for (int cf = 0; cf < 4; cf++) acc[cf] = (f32x4){0.f,0.f,0.f,0.f};

  const int nk = K >> 5;
  float avr[8], wvr[8];
  load_stage(A, W, ga, gfin, aMode, K, N, row0, col0, arow, akq, wcol, wkg, 0, avr, wvr);

  for (int s = 0; s < nk; s++){
    // split-cvt + LDS store (consumes avr/wvr of step s)
    int kgA = (s << 5) + akq*8;
    bf16x8 ah, al, wh, wl;
    #pragma unroll
    for (int j = 0; j < 8; j++){
      float vv = avr[j];
      if (aMode == 2) vv = ftanh(vv*bnsc[kgA+j] + bnsh[kgA+j]);
      __bf16 h = (__bf16)vv;
      ah[j] = h;
      al[j] = (__bf16)(vv - (float)h);
      float wvv = wvr[j];
      __bf16 wh_ = (__bf16)wvv;
      wh[j] = wh_;
      wl[j] = (__bf16)(wvv - (float)wh_);
    }
    *(bf16x8*)&As[0][arow][akq*8] = ah;
    *(bf16x8*)&As[1][arow][akq*8] = al;
    *(bf16x8*)&Ws[0][wcol][wkg*8] = wh;
    *(bf16x8*)&Ws[1][wcol][wkg*8] = wl;
    // prefetch next step (in flight across barrier)
    if (s + 1 < nk)
      load_stage(A, W, ga, gfin, aMode, K, N, row0, col0, arow, akq, wcol, wkg, s+1, avr, wvr);
    barrier_nodrain();

    bf16x8 afh = *(const bf16x8*)&As[0][w*16 + l15][l4*8];
    bf16x8 afl = *(const bf16x8*)&As[1][w*16 + l15][l4*8];
    #pragma unroll
    for (int cf = 0; cf < 4; cf++){
      bf16x8 bfh = *(const bf16x8*)&Ws[0][cf*16 + l15][l4*8];
      bf16x8 bfl = *(const bf16x8*)&Ws[1][cf*16 + l15][l4*8];
      acc[cf] = __builtin_amdgcn_mfma_f32_16x16x32_bf16(afh, bfh, acc[cf], 0, 0, 0);
      acc[cf] = __builtin_amdgcn_mfma_f32_16x16x32_bf16(afh, bfl, acc[cf], 0, 0, 0);
      acc[cf] = __builtin_amdgcn_mfma_f32_16x16x32_bf16(afl, bfh, acc[cf], 0, 0, 0);
    }
    barrier_nodrain();
  }

  // epilogue
  float vsum[4], vsq[4];
  #pragma unroll
  for (int cf = 0; cf < 4; cf++){ vsum[cf] = 0.f; vsq[cf] = 0.f; }
  #pragma unroll
  for (int cf = 0; cf < 4; cf++){
    int col = col0 + cf*16 + l15;
    #pragma unroll
    for (int r = 0; r < 4; r++){
      int row = row0 + w*16 + l4*4 + r;
      float v = acc[cf][r] + bias[col];
      if (addMode == 1) v += addsrc[(size_t)row*N + col];
      else if (addMode == 2) v += ftanh(addsrc[(size_t)row*512 + col]*bnsc[col] + bnsh[col]);
      if (dotanh) v = ftanh(v);
      out[(size_t)row*N + col] = v;
      vsum[cf] += v;
      vsq[cf]  += v*v;
    }
  }

  if (stats){
    __syncthreads();
    #pragma unroll
    for (int cf = 0; cf < 4; cf++) reds[w*4 + l4][cf*16 + l15] = vsum[cf];
    __syncthreads();
    if (tid < 64){
      float s = 0.f;
      #pragma unroll
      for (int r = 0; r < 16; r++) s += reds[r][tid];
      atomicAdd(&stats[col0 + tid], s);
    }
    __syncthreads();
    #pragma unroll
    for (int cf = 0; cf < 4; cf++) reds[w*4 + l4][cf*16 + l15] = vsq[cf];
    __syncthreads();
    if (tid < 64){
      float s = 0.f;
      #pragma unroll
      for (int r = 0; r < 16; r++) s += reds[r][tid];
      atomicAdd(&stats[512 + col0 + tid], s);
    }
  }
}

extern "C" void kernel_launch(void* const* d_in, const int* in_sizes, int n_in,
                              void* d_out, int out_size, void* d_ws, size_t ws_size,
                              hipStream_t stream){
  const float* x    = (const float*)d_in[0];
  const float* ga   = (const float*)d_in[1];
  const float* Wl   = (const float*)d_in[2];
  const float* bl   = (const float*)d_in[3];
  const float* Wr   = (const float*)d_in[4];
  const float* br   = (const float*)d_in[5];
  const float* att  = (const float*)d_in[6];
  const float* bout = (const float*)d_in[7];
  const float* gtok = (const float*)d_in[8];
  const float* m1pw = (const float*)d_in[9];
  const float* m1pb = (const float*)d_in[10];
  const float* m1w1 = (const float*)d_in[11];
  const float* m1b1 = (const float*)d_in[12];
  const float* m1w2 = (const float*)d_in[13];
  const float* m1b2 = (const float*)d_in[14];
  const float* bn1g = (const float*)d_in[15];
  const float* bn1b = (const float*)d_in[16];
  const float* m2w1 = (const float*)d_in[17];
  const float* m2b1 = (const float*)d_in[18];
  const float* m2w2 = (const float*)d_in[19];
  const float* m2b2 = (const float*)d_in[20];
  const float* bn2g = (const float*)d_in[21];
  const float* bn2b = (const float*)d_in[22];
  const float* m3pw = (const float*)d_in[23];
  const float* m3pb = (const float*)d_in[24];
  const float* m3w1 = (const float*)d_in[25];
  const float* m3b1 = (const float*)d_in[26];
  const float* m3w2 = (const float*)d_in[27];
  const float* m3b2 = (const float*)d_in[28];
  const int*   batch= (const int*)d_in[29];

  float* gout = (float*)d_out;              // [3][512][256]
  float* hout = (float*)d_out + 393216;     // [512][256]

  char* w = (char*)d_ws;
  __hip_bfloat16* wlt = (__hip_bfloat16*)(w + 0);   // 393216 B
  float*    cvec = (float*)(w + 393216);
  float*    ebuf = (float*)(w + 396288);
  // zero region (398336 floats):
  float*    gacc = (float*)(w + 2796288);
  float*    den  = (float*)(w + 4369152);
  unsigned* mkey = (unsigned*)(w + 4375296);
  float*    bns  = (float*)(w + 4381440);
  // head temps:
  float*    T1   = (float*)(w + 4389632);
  float*    P1   = (float*)(w + 5438208);
  float*    Hm   = (float*)(w + 6486784);
  float*    T2   = (float*)(w + 7535360);
  float*    H2   = (float*)(w + 8583936);
  float*    T3   = (float*)(w + 9632512);
  float*    P3   = (float*)(w + 10156800);

  kprep<<<435, 256, 0, stream>>>(Wl, wlt, Wr, bl, br, gtok, cvec, gacc);
  k1<<<512, 512, 0, stream>>>(x, wlt, cvec, att, batch, ebuf, mkey);
  kscan<<<dim3(782, 3), 256, 0, stream>>>(x, Wl, cvec, att, batch, ebuf, mkey, den, gacc);
  kgfinal<<<1536, 256, 0, stream>>>(gacc, den, bl, bout, gout);
  // S1: T1 = tanh(h0@m1w1+b1), P1 = h0@m1pw+pb  (gathered h0), K=832
  kmfma<<<dim3(8,8,2), 256, 0, stream>>>(nullptr, nullptr, ga, gout,
      nullptr, nullptr, nullptr, nullptr,
      m1w1, m1b1, T1, 1, m1pw, m1pb, P1, 0, 512, 832, 1, 0);
  // S2: Hm = T1@m1w2 + b2 + P1, bn1 stats
  kmfma<<<dim3(8,8,1), 256, 0, stream>>>(T1, P1, nullptr, nullptr,
      nullptr, nullptr, nullptr, bns,
      m1w2, m1b2, Hm, 0, nullptr, nullptr, nullptr, 0, 512, 512, 0, 1);
  // S3: T2 = tanh( tanh(bn1(Hm)) @ m2w1 + b1 )
  kmfma<<<dim3(8,8,1), 256, 0, stream>>>(Hm, nullptr, nullptr, nullptr,
      bns, bn1g, bn1b, nullptr,
      m2w1, m2b1, T2, 1, nullptr, nullptr, nullptr, 0, 512, 512, 2, 0);
  // S4: H2 = T2@m2w2 + b2 + tanh(bn1(Hm)), bn2 stats
  kmfma<<<dim3(8,8,1), 256, 0, stream>>>(T2, Hm, nullptr, nullptr,
      bns, bn1g, bn1b, bns + 1024,
      m2w2, m2b2, H2, 0, nullptr, nullptr, nullptr, 0, 512, 512, 0, 2);
  // S5: A = tanh(bn2(H2)); T3 = tanh(A@m3w1+b1), P3 = A@m3pw+pb  (N=256)
  kmfma<<<dim3(4,8,2), 256, 0, stream>>>(H2, nullptr, nullptr, nullptr,
      bns + 1024, bn2g, bn2b, nullptr,
      m3w1, m3b1, T3, 1, m3pw, m3pb, P3, 0, 256, 512, 2, 0);
  // S6: hout = T3@m3w2 + b2 + P3  (K=256)
  kmfma<<<dim3(4,8,1), 256, 0, stream>>>(T3, P3, nullptr, nullptr,
      nullptr, nullptr, nullptr, nullptr,
      m3w2, m3b2, hout, 0, nullptr, nullptr, nullptr, 0, 256, 256, 0, 1);
}

// Round 9
// 379.582 us; speedup vs baseline: 2.5783x; 1.0363x over previous
//
#include <hip/hip_runtime.h>
#include <hip/hip_bf16.h>

typedef __bf16 bf16x8 __attribute__((ext_vector_type(8)));
typedef float  f32x4  __attribute__((ext_vector_type(4)));

#define T_   3
#define N_   200000
#define C_   256
#define B_   512
#define EPSb 1e-5f

__device__ __forceinline__ unsigned enc_f(float f){
  unsigned u = __float_as_uint(f);
  return (u & 0x80000000u) ? ~u : (u | 0x80000000u);
}
__device__ __forceinline__ float dec_f(unsigned k){
  unsigned u = (k & 0x80000000u) ? (k ^ 0x80000000u) : ~k;
  return __uint_as_float(u);
}
// fast tanh: exact at +-inf, ~1e-6 rel err
__device__ __forceinline__ float ftanh(float x){
  float e = __expf(2.0f*x);
  return 1.0f - 2.0f/(e + 1.0f);
}

// raw barrier WITHOUT vmcnt drain (prefetch global loads stay in flight)
__device__ __forceinline__ void barrier_nodrain(){
  __builtin_amdgcn_sched_barrier(0);
  asm volatile("s_waitcnt lgkmcnt(0)" ::: "memory");
  __builtin_amdgcn_s_barrier();
  __builtin_amdgcn_sched_barrier(0);
}

// ---------------- prep: Wl transpose->bf16, cvec, zero-fill (one kernel)
__global__ void kprep(const float* __restrict__ Wl, __hip_bfloat16* __restrict__ wlt,
                      const float* __restrict__ Wr, const float* __restrict__ bl,
                      const float* __restrict__ br, const float* __restrict__ gtok,
                      float* __restrict__ cvec, float* __restrict__ zr){
  __shared__ float tile[64][65];
  __shared__ float gt[256];
  int blk = blockIdx.x, tid = threadIdx.x;
  if (blk < 48){
    int t = blk / 16, rem = blk % 16;
    int k0 = (rem >> 2)*64, c0 = (rem & 3)*64;
    int lc = tid & 63, lr0 = tid >> 6;
    #pragma unroll
    for (int q = 0; q < 16; q++){
      int lr = lr0*16 + q;
      tile[lr][lc] = Wl[t*65536 + (k0+lr)*256 + (c0+lc)];
    }
    __syncthreads();
    #pragma unroll
    for (int q = 0; q < 16; q++){
      int lr = lr0*16 + q;
      wlt[t*65536 + (c0+lr)*256 + (k0+lc)] = __float2bfloat16(tile[lc][lr]);
    }
  } else if (blk < 51){
    int t = blk - 48, c = tid;
    gt[tid] = gtok[t*256 + tid];
    __syncthreads();
    const float* wr = Wr + t*65536 + c;
    float a0=0.f,a1=0.f,a2=0.f,a3=0.f;
    #pragma unroll 2
    for (int k = 0; k < 256; k += 4){
      a0 += gt[k]  *wr[k*256];
      a1 += gt[k+1]*wr[(k+1)*256];
      a2 += gt[k+2]*wr[(k+2)*256];
      a3 += gt[k+3]*wr[(k+3)*256];
    }
    cvec[t*256 + c] = a0+a1+a2+a3 + bl[t*256+c] + br[t*256+c];
  } else {
    // zero region: gacc(393216)+den(1536)+mkey(1536)+bns(2048) floats
    for (int i = (blk-51)*256 + tid; i < 398336; i += (gridDim.x-51)*256) zr[i] = 0.f;
  }
}

// ---------------- big pass (contiguous ranges): e_approx = att.lrelu(x@Wl+cvec)
__global__ __launch_bounds__(512, 2)
void k1(const float* __restrict__ x, const __hip_bfloat16* __restrict__ wlt,
        const float* __restrict__ cvec, const float* __restrict__ att,
        const int* __restrict__ batch, float* __restrict__ e_out,
        unsigned* __restrict__ mkey){
  __shared__ __align__(16) __hip_bfloat16 Abuf[64][256];
  __shared__ float elds[4][64];
  const int tid = threadIdx.x;
  const int w = tid >> 6, l = tid & 63;
  const int wcol = w & 3, wrow = w >> 2;
  const int l15 = l & 15, l4 = l >> 4;
  const int srow = tid >> 3;
  const int sc   = tid & 7;
  const int sx   = srow & 7;

  bf16x8 bfr[8][4];
  float cv[4], at[4];
  int cur_t = -1;

  const int bid = blockIdx.x;
  const int nt = 18 + (bid < 159 ? 1 : 0);
  const int g0 = bid*18 + (bid < 159 ? bid : 159);

  f32x4 rg[8];
  {
    int t = g0 / 3125, tile = g0 % 3125;
    const float* xrow = x + (size_t)t*N_*256 + (size_t)(tile*64 + srow)*256;
    #pragma unroll
    for (int q = 0; q < 4; q++){
      int cs = (q*8 + sc) ^ sx;
      rg[2*q]   = *(const f32x4*)(xrow + cs*8);
      rg[2*q+1] = *(const f32x4*)(xrow + cs*8 + 4);
    }
  }

  for (int it = 0; it < nt; ++it){
    const int gt = g0 + it;
    const int t = gt / 3125, tile = gt % 3125;
    if (t != cur_t){
      cur_t = t;
      const __hip_bfloat16* WT = wlt + t*65536;
      #pragma unroll
      for (int fn = 0; fn < 4; fn++){
        int col = wcol*64 + fn*16 + l15;
        cv[fn] = cvec[t*256 + col];
        at[fn] = att[t*256 + col];
        #pragma unroll
        for (int ks = 0; ks < 8; ks++)
          bfr[ks][fn] = *(const bf16x8*)(WT + col*256 + ks*32 + l4*8);
      }
    }
    #pragma unroll
    for (int q = 0; q < 4; q++){
      bf16x8 v;
      #pragma unroll
      for (int j = 0; j < 4; j++){ v[j] = (__bf16)rg[2*q][j]; v[4+j] = (__bf16)rg[2*q+1][j]; }
      *(bf16x8*)(&Abuf[srow][(q*8 + sc)*8]) = v;
    }
    if (it + 1 < nt){
      int gn = gt + 1;
      int tn = gn / 3125, tilen = gn % 3125;
      const float* xrow = x + (size_t)tn*N_*256 + (size_t)(tilen*64 + srow)*256;
      #pragma unroll
      for (int q = 0; q < 4; q++){
        int cs = (q*8 + sc) ^ sx;
        rg[2*q]   = *(const f32x4*)(xrow + cs*8);
        rg[2*q+1] = *(const f32x4*)(xrow + cs*8 + 4);
      }
    }
    barrier_nodrain();

    f32x4 acc[2][4];
    #pragma unroll
    for (int fm = 0; fm < 2; fm++)
      #pragma unroll
      for (int fn = 0; fn < 4; fn++)
        acc[fm][fn] = (f32x4){0.f,0.f,0.f,0.f};

    #pragma unroll
    for (int ks = 0; ks < 8; ks++){
      bf16x8 a8[2];
      #pragma unroll
      for (int fm = 0; fm < 2; fm++){
        int row  = wrow*32 + fm*16 + l15;
        int slot = (ks*4 + l4) ^ (row & 7);
        a8[fm] = *(const bf16x8*)(&Abuf[row][slot*8]);
      }
      #pragma unroll
      for (int fm = 0; fm < 2; fm++)
        #pragma unroll
        for (int fn = 0; fn < 4; fn++)
          acc[fm][fn] = __builtin_amdgcn_mfma_f32_16x16x32_bf16(a8[fm], bfr[ks][fn], acc[fm][fn], 0, 0, 0);
    }

    #pragma unroll
    for (int fm = 0; fm < 2; fm++){
      #pragma unroll
      for (int r = 0; r < 4; r++){
        float v = 0.f;
        #pragma unroll
        for (int fn = 0; fn < 4; fn++){
          float xv = acc[fm][fn][r] + cv[fn];
          xv = (xv > 0.f) ? xv : 0.2f*xv;
          v += xv * at[fn];
        }
        v += __shfl_xor(v, 1);
        v += __shfl_xor(v, 2);
        v += __shfl_xor(v, 4);
        v += __shfl_xor(v, 8);
        if (l15 == 0) elds[wcol][wrow*32 + fm*16 + l4*4 + r] = v;
      }
    }
    barrier_nodrain();

    if (tid < 64){
      float ef = elds[0][tid] + elds[1][tid] + elds[2][tid] + elds[3][tid];
      int n = tile*64 + tid;
      e_out[t*N_ + n] = ef;
      int b = batch[t*N_ + n];
      float m = ef;
      #pragma unroll
      for (int off = 1; off < 64; off <<= 1){
        float up = __shfl_up(m, off);
        int   bu = __shfl_up(b, off);
        if (tid >= off && bu == b) m = fmaxf(m, up);
      }
      int bnx = __shfl_down(b, 1);
      if (tid == 63 || b != bnx) atomicMax(&mkey[t*B_ + b], enc_f(m));
    }
  }
}

// ---------------- fused select+candidate pass
__global__ void kscan(const float* __restrict__ x, const float* __restrict__ Wl,
                      const float* __restrict__ cvec, const float* __restrict__ att,
                      const int* __restrict__ batch, const float* __restrict__ e,
                      const unsigned* __restrict__ mkey,
                      float* __restrict__ den, float* __restrict__ gacc){
  __shared__ float xs[256];
  __shared__ float red[4];
  __shared__ float ebc;
  __shared__ int hits[256];
  __shared__ int nh;
  int t = blockIdx.y;
  int tid = threadIdx.x;
  int n0 = blockIdx.x*256;
  int n = n0 + tid;
  if (tid == 0) nh = 0;
  __syncthreads();
  if (n < N_){
    float ev = e[t*N_ + n];
    int b = batch[t*N_ + n];
    float m = dec_f(mkey[t*B_ + b]);
    if (ev >= m - 30.0f){ int p = atomicAdd(&nh, 1); hits[p] = tid; }
  }
  __syncthreads();
  int cnum = nh;
  for (int i = 0; i < cnum; i++){
    int hn = n0 + hits[i];
    xs[tid] = x[(size_t)t*N_*256 + (size_t)hn*256 + tid];
    __syncthreads();
    const float* wp = Wl + t*65536 + tid;
    float a0 = 0.f, a1 = 0.f;
    #pragma unroll 8
    for (int k = 0; k < 256; k += 2){
      a0 += xs[k]   * wp[k*256];
      a1 += xs[k+1] * wp[(k+1)*256];
    }
    float xl = a0 + a1;
    float xv = xl + cvec[t*256 + tid];
    xv = (xv > 0.f) ? xv : 0.2f*xv;
    float term = xv * att[t*256 + tid];
    #pragma unroll
    for (int off = 1; off < 64; off <<= 1) term += __shfl_xor(term, off);
    if ((tid & 63) == 0) red[tid >> 6] = term;
    __syncthreads();
    if (tid == 0) ebc = red[0] + red[1] + red[2] + red[3];
    __syncthreads();
    int b = batch[t*N_ + hn];
    float m = dec_f(mkey[t*B_ + b]);
    float wv = expf(ebc - m);
    if (tid == 0) atomicAdd(&den[t*B_ + b], wv);
    atomicAdd(&gacc[t*131072 + b*256 + tid], wv * xl);
    __syncthreads();
  }
}

// ---------------- finalize g
__global__ void kgfinal(const float* __restrict__ gacc, const float* __restrict__ den,
                        const float* __restrict__ bl, const float* __restrict__ bout,
                        float* __restrict__ gout){
  int i = blockIdx.x*256 + threadIdx.x;
  if (i >= 393216) return;
  int t = i >> 17, b = (i >> 8) & 511, c = i & 255;
  float d = den[t*B_ + b];
  float v = (d > 0.f) ? gacc[i]/d + bl[t*256+c] : 0.f;
  gout[i] = v + bout[t*256 + c];
}

// ---------------- staging loads for kmfma (BK=64: A 16 k's of one row; W one col 16 k's)
__device__ __forceinline__ void load_stage(const float* __restrict__ A,
    const float* __restrict__ W, const float* __restrict__ ga,
    const float* __restrict__ gfin, int aMode, int K, int N,
    int row0, int col0, int arow, int akq, int wcol, int wkg, int s,
    float* av, float* wv){
  int kg = (s << 6) + akq*16;
  const float* p;
  if (aMode == 0)      p = A + (size_t)(row0+arow)*K + kg;
  else if (aMode == 1) p = (kg < 64) ? ga + (size_t)(row0+arow)*64 + kg
                         : gfin + (size_t)((kg-64) >> 8)*131072 + (size_t)(row0+arow)*256 + ((kg-64) & 255);
  else                 p = A + (size_t)(row0+arow)*512 + kg;
  #pragma unroll
  for (int q = 0; q < 4; q++){
    f32x4 v = *(const f32x4*)(p + q*4);
    av[q*4+0]=v[0]; av[q*4+1]=v[1]; av[q*4+2]=v[2]; av[q*4+3]=v[3];
  }
  const float* q = W + (size_t)((s << 6) + wkg*16)*N + col0 + wcol;
  #pragma unroll
  for (int j = 0; j < 16; j++) wv[j] = q[(size_t)j*N];
}

// ---------------- MFMA head GEMM, split-bf16 error compensation, BK=64:
// each operand v = hi + lo (bf16 pair); acc += hi*hi + hi*lo + lo*hi.
__global__ __launch_bounds__(256)
void kmfma(const float* __restrict__ A, const float* __restrict__ addsrc,
           const float* __restrict__ ga, const float* __restrict__ gfin,
           const float* __restrict__ bnsums, const float* __restrict__ bng,
           const float* __restrict__ bnb, float* __restrict__ stats,
           const float* __restrict__ W0, const float* __restrict__ bias0,
           float* __restrict__ out0, int tanh0,
           const float* __restrict__ W1, const float* __restrict__ bias1,
           float* __restrict__ out1, int tanh1,
           int N, int K, int aMode, int addMode){
  __shared__ __align__(16) __bf16 As[2][64][72];   // [hi/lo][row][k0..63] pad 72
  __shared__ __align__(16) __bf16 Ws[2][64][72];   // [hi/lo][col][k0..63]
  __shared__ float bnsc[512], bnsh[512];
  __shared__ float reds[16][64];

  const float* W = W0; const float* bias = bias0; float* out = out0; int dotanh = tanh0;
  if (blockIdx.z){ W = W1; bias = bias1; out = out1; dotanh = tanh1; }

  const int tid = threadIdx.x;
  const int w = tid >> 6, l = tid & 63;
  const int l15 = l & 15, l4 = l >> 4;
  const int row0 = blockIdx.y*64, col0 = blockIdx.x*64;
  const int arow = tid >> 2, akq = tid & 3;   // A stage: row 0..63, 16-k chunk 0..3
  const int wcol = tid & 63, wkg = tid >> 6;  // W stage: col 0..63, 16-k chunk 0..3

  if (aMode == 2 || addMode == 2){
    #pragma unroll
    for (int q = 0; q < 2; q++){
      int k = q*256 + tid;
      float mu = bnsums[k] * (1.f/512.f);
      float var = bnsums[512+k] * (1.f/512.f) - mu*mu;
      float sc = bng[k] * __frsqrt_rn(var + EPSb);
      bnsc[k] = sc;
      bnsh[k] = bnb[k] - mu*sc;
    }
    __syncthreads();
  }

  f32x4 acc[4];
  #pragma unroll
  for (int cf = 0; cf < 4; cf++) acc[cf] = (f32x4){0.f,0.f,0.f,0.f};

  const int nk = K >> 6;
  float avr[16], wvr[16];
  load_stage(A, W, ga, gfin, aMode, K, N, row0, col0, arow, akq, wcol, wkg, 0, avr, wvr);

  for (int s = 0; s < nk; s++){
    // split-cvt + LDS store (consumes avr/wvr of step s)
    int kgA = (s << 6) + akq*16;
    bf16x8 ah[2], al[2], wh[2], wl[2];
    #pragma unroll
    for (int half = 0; half < 2; half++){
      #pragma unroll
      for (int j = 0; j < 8; j++){
        float vv = avr[half*8 + j];
        if (aMode == 2) vv = ftanh(vv*bnsc[kgA + half*8 + j] + bnsh[kgA + half*8 + j]);
        __bf16 h = (__bf16)vv;
        ah[half][j] = h;
        al[half][j] = (__bf16)(vv - (float)h);
        float wvv = wvr[half*8 + j];
        __bf16 wh_ = (__bf16)wvv;
        wh[half][j] = wh_;
        wl[half][j] = (__bf16)(wvv - (float)wh_);
      }
    }
    *(bf16x8*)&As[0][arow][akq*16]     = ah[0];
    *(bf16x8*)&As[0][arow][akq*16 + 8] = ah[1];
    *(bf16x8*)&As[1][arow][akq*16]     = al[0];
    *(bf16x8*)&As[1][arow][akq*16 + 8] = al[1];
    *(bf16x8*)&Ws[0][wcol][wkg*16]     = wh[0];
    *(bf16x8*)&Ws[0][wcol][wkg*16 + 8] = wh[1];
    *(bf16x8*)&Ws[1][wcol][wkg*16]     = wl[0];
    *(bf16x8*)&Ws[1][wcol][wkg*16 + 8] = wl[1];
    // prefetch next step (in flight across barrier)
    if (s + 1 < nk)
      load_stage(A, W, ga, gfin, aMode, K, N, row0, col0, arow, akq, wcol, wkg, s+1, avr, wvr);
    barrier_nodrain();

    #pragma unroll
    for (int h = 0; h < 2; h++){
      bf16x8 afh = *(const bf16x8*)&As[0][w*16 + l15][h*32 + l4*8];
      bf16x8 afl = *(const bf16x8*)&As[1][w*16 + l15][h*32 + l4*8];
      #pragma unroll
      for (int cf = 0; cf < 4; cf++){
        bf16x8 bfh = *(const bf16x8*)&Ws[0][cf*16 + l15][h*32 + l4*8];
        bf16x8 bfl = *(const bf16x8*)&Ws[1][cf*16 + l15][h*32 + l4*8];
        acc[cf] = __builtin_amdgcn_mfma_f32_16x16x32_bf16(afh, bfh, acc[cf], 0, 0, 0);
        acc[cf] = __builtin_amdgcn_mfma_f32_16x16x32_bf16(afh, bfl, acc[cf], 0, 0, 0);
        acc[cf] = __builtin_amdgcn_mfma_f32_16x16x32_bf16(afl, bfh, acc[cf], 0, 0, 0);
      }
    }
    barrier_nodrain();
  }

  // epilogue
  float vsum[4], vsq[4];
  #pragma unroll
  for (int cf = 0; cf < 4; cf++){ vsum[cf] = 0.f; vsq[cf] = 0.f; }
  #pragma unroll
  for (int cf = 0; cf < 4; cf++){
    int col = col0 + cf*16 + l15;
    #pragma unroll
    for (int r = 0; r < 4; r++){
      int row = row0 + w*16 + l4*4 + r;
      float v = acc[cf][r] + bias[col];
      if (addMode == 1) v += addsrc[(size_t)row*N + col];
      else if (addMode == 2) v += ftanh(addsrc[(size_t)row*512 + col]*bnsc[col] + bnsh[col]);
      if (dotanh) v = ftanh(v);
      out[(size_t)row*N + col] = v;
      vsum[cf] += v;
      vsq[cf]  += v*v;
    }
  }

  if (stats){
    __syncthreads();
    #pragma unroll
    for (int cf = 0; cf < 4; cf++) reds[w*4 + l4][cf*16 + l15] = vsum[cf];
    __syncthreads();
    if (tid < 64){
      float s = 0.f;
      #pragma unroll
      for (int r = 0; r < 16; r++) s += reds[r][tid];
      atomicAdd(&stats[col0 + tid], s);
    }
    __syncthreads();
    #pragma unroll
    for (int cf = 0; cf < 4; cf++) reds[w*4 + l4][cf*16 + l15] = vsq[cf];
    __syncthreads();
    if (tid < 64){
      float s = 0.f;
      #pragma unroll
      for (int r = 0; r < 16; r++) s += reds[r][tid];
      atomicAdd(&stats[512 + col0 + tid], s);
    }
  }
}

extern "C" void kernel_launch(void* const* d_in, const int* in_sizes, int n_in,
                              void* d_out, int out_size, void* d_ws, size_t ws_size,
                              hipStream_t stream){
  const float* x    = (const float*)d_in[0];
  const float* ga   = (const float*)d_in[1];
  const float* Wl   = (const float*)d_in[2];
  const float* bl   = (const float*)d_in[3];
  const float* Wr   = (const float*)d_in[4];
  const float* br   = (const float*)d_in[5];
  const float* att  = (const float*)d_in[6];
  const float* bout = (const float*)d_in[7];
  const float* gtok = (const float*)d_in[8];
  const float* m1pw = (const float*)d_in[9];
  const float* m1pb = (const float*)d_in[10];
  const float* m1w1 = (const float*)d_in[11];
  const float* m1b1 = (const float*)d_in[12];
  const float* m1w2 = (const float*)d_in[13];
  const float* m1b2 = (const float*)d_in[14];
  const float* bn1g = (const float*)d_in[15];
  const float* bn1b = (const float*)d_in[16];
  const float* m2w1 = (const float*)d_in[17];
  const float* m2b1 = (const float*)d_in[18];
  const float* m2w2 = (const float*)d_in[19];
  const float* m2b2 = (const float*)d_in[20];
  const float* bn2g = (const float*)d_in[21];
  const float* bn2b = (const float*)d_in[22];
  const float* m3pw = (const float*)d_in[23];
  const float* m3pb = (const float*)d_in[24];
  const float* m3w1 = (const float*)d_in[25];
  const float* m3b1 = (const float*)d_in[26];
  const float* m3w2 = (const float*)d_in[27];
  const float* m3b2 = (const float*)d_in[28];
  const int*   batch= (const int*)d_in[29];

  float* gout = (float*)d_out;              // [3][512][256]
  float* hout = (float*)d_out + 393216;     // [512][256]

  char* w = (char*)d_ws;
  __hip_bfloat16* wlt = (__hip_bfloat16*)(w + 0);   // 393216 B
  float*    cvec = (float*)(w + 393216);
  float*    ebuf = (float*)(w + 396288);
  // zero region (398336 floats):
  float*    gacc = (float*)(w + 2796288);
  float*    den  = (float*)(w + 4369152);
  unsigned* mkey = (unsigned*)(w + 4375296);
  float*    bns  = (float*)(w + 4381440);
  // head temps:
  float*    T1   = (float*)(w + 4389632);
  float*    P1   = (float*)(w + 5438208);
  float*    Hm   = (float*)(w + 6486784);
  float*    T2   = (float*)(w + 7535360);
  float*    H2   = (float*)(w + 8583936);
  float*    T3   = (float*)(w + 9632512);
  float*    P3   = (float*)(w + 10156800);

  kprep<<<435, 256, 0, stream>>>(Wl, wlt, Wr, bl, br, gtok, cvec, gacc);
  k1<<<512, 512, 0, stream>>>(x, wlt, cvec, att, batch, ebuf, mkey);
  kscan<<<dim3(782, 3), 256, 0, stream>>>(x, Wl, cvec, att, batch, ebuf, mkey, den, gacc);
  kgfinal<<<1536, 256, 0, stream>>>(gacc, den, bl, bout, gout);
  // S1: T1 = tanh(h0@m1w1+b1), P1 = h0@m1pw+pb  (gathered h0), K=832
  kmfma<<<dim3(8,8,2), 256, 0, stream>>>(nullptr, nullptr, ga, gout,
      nullptr, nullptr, nullptr, nullptr,
      m1w1, m1b1, T1, 1, m1pw, m1pb, P1, 0, 512, 832, 1, 0);
  // S2: Hm = T1@m1w2 + b2 + P1, bn1 stats
  kmfma<<<dim3(8,8,1), 256, 0, stream>>>(T1, P1, nullptr, nullptr,
      nullptr, nullptr, nullptr, bns,
      m1w2, m1b2, Hm, 0, nullptr, nullptr, nullptr, 0, 512, 512, 0, 1);
  // S3: T2 = tanh( tanh(bn1(Hm)) @ m2w1 + b1 )
  kmfma<<<dim3(8,8,1), 256, 0, stream>>>(Hm, nullptr, nullptr, nullptr,
      bns, bn1g, bn1b, nullptr,
      m2w1, m2b1, T2, 1, nullptr, nullptr, nullptr, 0, 512, 512, 2, 0);
  // S4: H2 = T2@m2w2 + b2 + tanh(bn1(Hm)), bn2 stats
  kmfma<<<dim3(8,8,1), 256, 0, stream>>>(T2, Hm, nullptr, nullptr,
      bns, bn1g, bn1b, bns + 1024,
      m2w2, m2b2, H2, 0, nullptr, nullptr, nullptr, 0, 512, 512, 0, 2);
  // S5: A = tanh(bn2(H2)); T3 = tanh(A@m3w1+b1), P3 = A@m3pw+pb  (N=256)
  kmfma<<<dim3(4,8,2), 256, 0, stream>>>(H2, nullptr, nullptr, nullptr,
      bns + 1024, bn2g, bn2b, nullptr,
      m3w1, m3b1, T3, 1, m3pw, m3pb, P3, 0, 256, 512, 2, 0);
  // S6: hout = T3@m3w2 + b2 + P3  (K=256)
  kmfma<<<dim3(4,8,1), 256, 0, stream>>>(T3, P3, nullptr, nullptr,
      nullptr, nullptr, nullptr, nullptr,
      m3w2, m3b2, hout, 0, nullptr, nullptr, nullptr, 0, 256, 256, 0, 1);
}

// Round 10
// 374.771 us; speedup vs baseline: 2.6114x; 1.0128x over previous
//
#include <hip/hip_runtime.h>
#include <hip/hip_bf16.h>

typedef __bf16 bf16x8 __attribute__((ext_vector_type(8)));
typedef float  f32x4  __attribute__((ext_vector_type(4)));

#define T_   3
#define N_   200000
#define C_   256
#define B_   512
#define EPSb 1e-5f

__device__ __forceinline__ unsigned enc_f(float f){
  unsigned u = __float_as_uint(f);
  return (u & 0x80000000u) ? ~u : (u | 0x80000000u);
}
__device__ __forceinline__ float dec_f(unsigned k){
  unsigned u = (k & 0x80000000u) ? (k ^ 0x80000000u) : ~k;
  return __uint_as_float(u);
}
// fast tanh: exact at +-inf, ~1e-6 rel err
__device__ __forceinline__ float ftanh(float x){
  float e = __expf(2.0f*x);
  return 1.0f - 2.0f/(e + 1.0f);
}

// raw barrier WITHOUT vmcnt drain (prefetch loads stay in flight)
__device__ __forceinline__ void barrier_nodrain(){
  __builtin_amdgcn_sched_barrier(0);
  asm volatile("s_waitcnt lgkmcnt(0)" ::: "memory");
  __builtin_amdgcn_s_barrier();
  __builtin_amdgcn_sched_barrier(0);
}

__device__ __forceinline__ void gload_lds16(const float* src, float* lds_dst){
  __builtin_amdgcn_global_load_lds(
      (const __attribute__((address_space(1))) unsigned*)src,
      (__attribute__((address_space(3))) unsigned*)lds_dst, 16, 0, 0);
}

// ---------------- prep: Wl transpose->bf16, cvec, zero-fill (one kernel)
__global__ void kprep(const float* __restrict__ Wl, __hip_bfloat16* __restrict__ wlt,
                      const float* __restrict__ Wr, const float* __restrict__ bl,
                      const float* __restrict__ br, const float* __restrict__ gtok,
                      float* __restrict__ cvec, float* __restrict__ zr){
  __shared__ float tile[64][65];
  __shared__ float gt[256];
  int blk = blockIdx.x, tid = threadIdx.x;
  if (blk < 48){
    int t = blk / 16, rem = blk % 16;
    int k0 = (rem >> 2)*64, c0 = (rem & 3)*64;
    int lc = tid & 63, lr0 = tid >> 6;
    #pragma unroll
    for (int q = 0; q < 16; q++){
      int lr = lr0*16 + q;
      tile[lr][lc] = Wl[t*65536 + (k0+lr)*256 + (c0+lc)];
    }
    __syncthreads();
    #pragma unroll
    for (int q = 0; q < 16; q++){
      int lr = lr0*16 + q;
      wlt[t*65536 + (c0+lr)*256 + (k0+lc)] = __float2bfloat16(tile[lc][lr]);
    }
  } else if (blk < 51){
    int t = blk - 48, c = tid;
    gt[tid] = gtok[t*256 + tid];
    __syncthreads();
    const float* wr = Wr + t*65536 + c;
    float a0=0.f,a1=0.f,a2=0.f,a3=0.f;
    #pragma unroll 2
    for (int k = 0; k < 256; k += 4){
      a0 += gt[k]  *wr[k*256];
      a1 += gt[k+1]*wr[(k+1)*256];
      a2 += gt[k+2]*wr[(k+2)*256];
      a3 += gt[k+3]*wr[(k+3)*256];
    }
    cvec[t*256 + c] = a0+a1+a2+a3 + bl[t*256+c] + br[t*256+c];
  } else {
    // zero region: gacc(393216)+den(1536)+mkey(1536)+bns(2048) floats
    for (int i = (blk-51)*256 + tid; i < 398336; i += (gridDim.x-51)*256) zr[i] = 0.f;
  }
}

// ---------------- big pass: e_approx = att.lrelu(x@Wl+cvec)
// x staged fp32 to LDS via global_load_lds DMA, double-buffered, counted vmcnt.
// LDS slot swizzle: row r, 16B-chunk slot s holds global chunk s^(r&7)
// (DMA dest is lane-linear; global SOURCE is pre-swizzled -> rule #21).
__global__ __launch_bounds__(512)
void k1(const float* __restrict__ x, const __hip_bfloat16* __restrict__ wlt,
        const float* __restrict__ cvec, const float* __restrict__ att,
        const int* __restrict__ batch, float* __restrict__ e_out,
        unsigned* __restrict__ mkey){
  __shared__ __align__(16) float Af[2][64][256];   // 128 KB
  __shared__ float elds[4][64];
  const int tid = threadIdx.x;
  const int w = tid >> 6, l = tid & 63;
  const int wcol = w & 3, wrow = w >> 2;
  const int l15 = l & 15, l4 = l >> 4;

  bf16x8 bfr[8][4];
  float cv[4], at[4];
  int cur_t = -1;

  const int bid = blockIdx.x;
  const int nt = 36 + (bid < 159 ? 1 : 0);
  const int g0 = bid*36 + (bid < 159 ? bid : 159);

  // prologue DMA: tile g0 -> buf0 (wave w owns rows w*8..w*8+7)
  {
    int t0 = g0 / 3125, tile0 = g0 % 3125;
    const float* xb = x + (size_t)t0*N_*256 + (size_t)tile0*64*256;
    #pragma unroll
    for (int i = 0; i < 8; i++){
      int r = w*8 + i;
      gload_lds16(xb + (size_t)r*256 + ((l ^ i) << 2), &Af[0][r][0]);
    }
  }

  for (int it = 0; it < nt; ++it){
    const int gt = g0 + it;
    const int t = gt / 3125, tile = gt % 3125;
    if (t != cur_t){
      cur_t = t;
      const __hip_bfloat16* WT = wlt + t*65536;
      #pragma unroll
      for (int fn = 0; fn < 4; fn++){
        int col = wcol*64 + fn*16 + l15;
        cv[fn] = cvec[t*256 + col];
        at[fn] = att[t*256 + col];
        #pragma unroll
        for (int ks = 0; ks < 8; ks++)
          bfr[ks][fn] = *(const bf16x8*)(WT + col*256 + ks*32 + l4*8);
      }
    }
    const float* Ab = &Af[it & 1][0][0];

    // issue next-tile DMA into the other buffer; counted wait for current
    if (it + 1 < nt){
      int gn = gt + 1;
      int tn = gn / 3125, tilen = gn % 3125;
      const float* xb = x + (size_t)tn*N_*256 + (size_t)tilen*64*256;
      float* Dn = &Af[(it+1) & 1][0][0];
      #pragma unroll
      for (int i = 0; i < 8; i++){
        int r = w*8 + i;
        gload_lds16(xb + (size_t)r*256 + ((l ^ i) << 2), Dn + r*256);
      }
      __builtin_amdgcn_sched_barrier(0);
      asm volatile("s_waitcnt vmcnt(8)" ::: "memory");   // current buf done; 8 new stay in flight
      __builtin_amdgcn_sched_barrier(0);
    } else {
      __builtin_amdgcn_sched_barrier(0);
      asm volatile("s_waitcnt vmcnt(0)" ::: "memory");
      __builtin_amdgcn_sched_barrier(0);
    }
    __builtin_amdgcn_s_barrier();   // all waves' DMA for current buf complete
    __builtin_amdgcn_sched_barrier(0);

    f32x4 acc[2][4];
    #pragma unroll
    for (int fm = 0; fm < 2; fm++)
      #pragma unroll
      for (int fn = 0; fn < 4; fn++)
        acc[fm][fn] = (f32x4){0.f,0.f,0.f,0.f};

    #pragma unroll
    for (int ks = 0; ks < 8; ks++){
      bf16x8 a8[2];
      #pragma unroll
      for (int fm = 0; fm < 2; fm++){
        int row = wrow*32 + fm*16 + l15;
        int sxr = row & 7;
        int c0 = ks*8 + l4*2;
        const float* rp = Ab + row*256;
        f32x4 p0 = *(const f32x4*)(rp + (((c0    ) ^ sxr) << 2));
        f32x4 p1 = *(const f32x4*)(rp + (((c0 + 1) ^ sxr) << 2));
        #pragma unroll
        for (int j = 0; j < 4; j++){ a8[fm][j] = (__bf16)p0[j]; a8[fm][4+j] = (__bf16)p1[j]; }
      }
      #pragma unroll
      for (int fm = 0; fm < 2; fm++)
        #pragma unroll
        for (int fn = 0; fn < 4; fn++)
          acc[fm][fn] = __builtin_amdgcn_mfma_f32_16x16x32_bf16(a8[fm], bfr[ks][fn], acc[fm][fn], 0, 0, 0);
    }

    #pragma unroll
    for (int fm = 0; fm < 2; fm++){
      #pragma unroll
      for (int r = 0; r < 4; r++){
        float v = 0.f;
        #pragma unroll
        for (int fn = 0; fn < 4; fn++){
          float xv = acc[fm][fn][r] + cv[fn];
          xv = (xv > 0.f) ? xv : 0.2f*xv;
          v += xv * at[fn];
        }
        v += __shfl_xor(v, 1);
        v += __shfl_xor(v, 2);
        v += __shfl_xor(v, 4);
        v += __shfl_xor(v, 8);
        if (l15 == 0) elds[wcol][wrow*32 + fm*16 + l4*4 + r] = v;
      }
    }
    barrier_nodrain();   // elds visible; all buf reads drained before next DMA overwrite

    if (tid < 64){
      float ef = elds[0][tid] + elds[1][tid] + elds[2][tid] + elds[3][tid];
      int n = tile*64 + tid;
      e_out[t*N_ + n] = ef;
      int b = batch[t*N_ + n];
      float m = ef;
      #pragma unroll
      for (int off = 1; off < 64; off <<= 1){
        float up = __shfl_up(m, off);
        int   bu = __shfl_up(b, off);
        if (tid >= off && bu == b) m = fmaxf(m, up);
      }
      int bnx = __shfl_down(b, 1);
      if (tid == 63 || b != bnx) atomicMax(&mkey[t*B_ + b], enc_f(m));
    }
  }
}

// ---------------- fused select+candidate pass
__global__ void kscan(const float* __restrict__ x, const float* __restrict__ Wl,
                      const float* __restrict__ cvec, const float* __restrict__ att,
                      const int* __restrict__ batch, const float* __restrict__ e,
                      const unsigned* __restrict__ mkey,
                      float* __restrict__ den, float* __restrict__ gacc){
  __shared__ float xs[256];
  __shared__ float red[4];
  __shared__ float ebc;
  __shared__ int hits[256];
  __shared__ int nh;
  int t = blockIdx.y;
  int tid = threadIdx.x;
  int n0 = blockIdx.x*256;
  int n = n0 + tid;
  if (tid == 0) nh = 0;
  __syncthreads();
  if (n < N_){
    float ev = e[t*N_ + n];
    int b = batch[t*N_ + n];
    float m = dec_f(mkey[t*B_ + b]);
    if (ev >= m - 30.0f){ int p = atomicAdd(&nh, 1); hits[p] = tid; }
  }
  __syncthreads();
  int cnum = nh;
  for (int i = 0; i < cnum; i++){
    int hn = n0 + hits[i];
    xs[tid] = x[(size_t)t*N_*256 + (size_t)hn*256 + tid];
    __syncthreads();
    const float* wp = Wl + t*65536 + tid;
    float a0 = 0.f, a1 = 0.f;
    #pragma unroll 8
    for (int k = 0; k < 256; k += 2){
      a0 += xs[k]   * wp[k*256];
      a1 += xs[k+1] * wp[(k+1)*256];
    }
    float xl = a0 + a1;
    float xv = xl + cvec[t*256 + tid];
    xv = (xv > 0.f) ? xv : 0.2f*xv;
    float term = xv * att[t*256 + tid];
    #pragma unroll
    for (int off = 1; off < 64; off <<= 1) term += __shfl_xor(term, off);
    if ((tid & 63) == 0) red[tid >> 6] = term;
    __syncthreads();
    if (tid == 0) ebc = red[0] + red[1] + red[2] + red[3];
    __syncthreads();
    int b = batch[t*N_ + hn];
    float m = dec_f(mkey[t*B_ + b]);
    float wv = expf(ebc - m);
    if (tid == 0) atomicAdd(&den[t*B_ + b], wv);
    atomicAdd(&gacc[t*131072 + b*256 + tid], wv * xl);
    __syncthreads();
  }
}

// ---------------- finalize g
__global__ void kgfinal(const float* __restrict__ gacc, const float* __restrict__ den,
                        const float* __restrict__ bl, const float* __restrict__ bout,
                        float* __restrict__ gout){
  int i = blockIdx.x*256 + threadIdx.x;
  if (i >= 393216) return;
  int t = i >> 17, b = (i >> 8) & 511, c = i & 255;
  float d = den[t*B_ + b];
  float v = (d > 0.f) ? gacc[i]/d + bl[t*256+c] : 0.f;
  gout[i] = v + bout[t*256 + c];
}

// ---------------- staging loads for kmfma (BK=64)
__device__ __forceinline__ void load_stage(const float* __restrict__ A,
    const float* __restrict__ W, const float* __restrict__ ga,
    const float* __restrict__ gfin, int aMode, int K, int N,
    int row0, int col0, int arow, int akq, int wcol, int wkg, int s,
    float* av, float* wv){
  int kg = (s << 6) + akq*16;
  const float* p;
  if (aMode == 0)      p = A + (size_t)(row0+arow)*K + kg;
  else if (aMode == 1) p = (kg < 64) ? ga + (size_t)(row0+arow)*64 + kg
                         : gfin + (size_t)((kg-64) >> 8)*131072 + (size_t)(row0+arow)*256 + ((kg-64) & 255);
  else                 p = A + (size_t)(row0+arow)*512 + kg;
  #pragma unroll
  for (int q = 0; q < 4; q++){
    f32x4 v = *(const f32x4*)(p + q*4);
    av[q*4+0]=v[0]; av[q*4+1]=v[1]; av[q*4+2]=v[2]; av[q*4+3]=v[3];
  }
  const float* q = W + (size_t)((s << 6) + wkg*16)*N + col0 + wcol;
  #pragma unroll
  for (int j = 0; j < 16; j++) wv[j] = q[(size_t)j*N];
}

// ---------------- MFMA head GEMM, split-bf16 error compensation, BK=64
__global__ __launch_bounds__(256)
void kmfma(const float* __restrict__ A, const float* __restrict__ addsrc,
           const float* __restrict__ ga, const float* __restrict__ gfin,
           const float* __restrict__ bnsums, const float* __restrict__ bng,
           const float* __restrict__ bnb, float* __restrict__ stats,
           const float* __restrict__ W0, const float* __restrict__ bias0,
           float* __restrict__ out0, int tanh0,
           const float* __restrict__ W1, const float* __restrict__ bias1,
           float* __restrict__ out1, int tanh1,
           int N, int K, int aMode, int addMode){
  __shared__ __align__(16) __bf16 As[2][64][72];
  __shared__ __align__(16) __bf16 Ws[2][64][72];
  __shared__ float bnsc[512], bnsh[512];
  __shared__ float reds[16][64];

  const float* W = W0; const float* bias = bias0; float* out = out0; int dotanh = tanh0;
  if (blockIdx.z){ W = W1; bias = bias1; out = out1; dotanh = tanh1; }

  const int tid = threadIdx.x;
  const int w = tid >> 6, l = tid & 63;
  const int l15 = l & 15, l4 = l >> 4;
  const int row0 = blockIdx.y*64, col0 = blockIdx.x*64;
  const int arow = tid >> 2, akq = tid & 3;
  const int wcol = tid & 63, wkg = tid >> 6;

  if (aMode == 2 || addMode == 2){
    #pragma unroll
    for (int q = 0; q < 2; q++){
      int k = q*256 + tid;
      float mu = bnsums[k] * (1.f/512.f);
      float var = bnsums[512+k] * (1.f/512.f) - mu*mu;
      float sc = bng[k] * __frsqrt_rn(var + EPSb);
      bnsc[k] = sc;
      bnsh[k] = bnb[k] - mu*sc;
    }
    __syncthreads();
  }

  f32x4 acc[4];
  #pragma unroll
  for (int cf = 0; cf < 4; cf++) acc[cf] = (f32x4){0.f,0.f,0.f,0.f};

  const int nk = K >> 6;
  float avr[16], wvr[16];
  load_stage(A, W, ga, gfin, aMode, K, N, row0, col0, arow, akq, wcol, wkg, 0, avr, wvr);

  for (int s = 0; s < nk; s++){
    int kgA = (s << 6) + akq*16;
    bf16x8 ah[2], al[2], wh[2], wl[2];
    #pragma unroll
    for (int half = 0; half < 2; half++){
      #pragma unroll
      for (int j = 0; j < 8; j++){
        float vv = avr[half*8 + j];
        if (aMode == 2) vv = ftanh(vv*bnsc[kgA + half*8 + j] + bnsh[kgA + half*8 + j]);
        __bf16 h = (__bf16)vv;
        ah[half][j] = h;
        al[half][j] = (__bf16)(vv - (float)h);
        float wvv = wvr[half*8 + j];
        __bf16 wh_ = (__bf16)wvv;
        wh[half][j] = wh_;
        wl[half][j] = (__bf16)(wvv - (float)wh_);
      }
    }
    *(bf16x8*)&As[0][arow][akq*16]     = ah[0];
    *(bf16x8*)&As[0][arow][akq*16 + 8] = ah[1];
    *(bf16x8*)&As[1][arow][akq*16]     = al[0];
    *(bf16x8*)&As[1][arow][akq*16 + 8] = al[1];
    *(bf16x8*)&Ws[0][wcol][wkg*16]     = wh[0];
    *(bf16x8*)&Ws[0][wcol][wkg*16 + 8] = wh[1];
    *(bf16x8*)&Ws[1][wcol][wkg*16]     = wl[0];
    *(bf16x8*)&Ws[1][wcol][wkg*16 + 8] = wl[1];
    if (s + 1 < nk)
      load_stage(A, W, ga, gfin, aMode, K, N, row0, col0, arow, akq, wcol, wkg, s+1, avr, wvr);
    barrier_nodrain();

    #pragma unroll
    for (int h = 0; h < 2; h++){
      bf16x8 afh = *(const bf16x8*)&As[0][w*16 + l15][h*32 + l4*8];
      bf16x8 afl = *(const bf16x8*)&As[1][w*16 + l15][h*32 + l4*8];
      #pragma unroll
      for (int cf = 0; cf < 4; cf++){
        bf16x8 bfh = *(const bf16x8*)&Ws[0][cf*16 + l15][h*32 + l4*8];
        bf16x8 bfl = *(const bf16x8*)&Ws[1][cf*16 + l15][h*32 + l4*8];
        acc[cf] = __builtin_amdgcn_mfma_f32_16x16x32_bf16(afh, bfh, acc[cf], 0, 0, 0);
        acc[cf] = __builtin_amdgcn_mfma_f32_16x16x32_bf16(afh, bfl, acc[cf], 0, 0, 0);
        acc[cf] = __builtin_amdgcn_mfma_f32_16x16x32_bf16(afl, bfh, acc[cf], 0, 0, 0);
      }
    }
    barrier_nodrain();
  }

  float vsum[4], vsq[4];
  #pragma unroll
  for (int cf = 0; cf < 4; cf++){ vsum[cf] = 0.f; vsq[cf] = 0.f; }
  #pragma unroll
  for (int cf = 0; cf < 4; cf++){
    int col = col0 + cf*16 + l15;
    #pragma unroll
    for (int r = 0; r < 4; r++){
      int row = row0 + w*16 + l4*4 + r;
      float v = acc[cf][r] + bias[col];
      if (addMode == 1) v += addsrc[(size_t)row*N + col];
      else if (addMode == 2) v += ftanh(addsrc[(size_t)row*512 + col]*bnsc[col] + bnsh[col]);
      if (dotanh) v = ftanh(v);
      out[(size_t)row*N + col] = v;
      vsum[cf] += v;
      vsq[cf]  += v*v;
    }
  }

  if (stats){
    __syncthreads();
    #pragma unroll
    for (int cf = 0; cf < 4; cf++) reds[w*4 + l4][cf*16 + l15] = vsum[cf];
    __syncthreads();
    if (tid < 64){
      float s = 0.f;
      #pragma unroll
      for (int r = 0; r < 16; r++) s += reds[r][tid];
      atomicAdd(&stats[col0 + tid], s);
    }
    __syncthreads();
    #pragma unroll
    for (int cf = 0; cf < 4; cf++) reds[w*4 + l4][cf*16 + l15] = vsq[cf];
    __syncthreads();
    if (tid < 64){
      float s = 0.f;
      #pragma unroll
      for (int r = 0; r < 16; r++) s += reds[r][tid];
      atomicAdd(&stats[512 + col0 + tid], s);
    }
  }
}

extern "C" void kernel_launch(void* const* d_in, const int* in_sizes, int n_in,
                              void* d_out, int out_size, void* d_ws, size_t ws_size,
                              hipStream_t stream){
  const float* x    = (const float*)d_in[0];
  const float* ga   = (const float*)d_in[1];
  const float* Wl   = (const float*)d_in[2];
  const float* bl   = (const float*)d_in[3];
  const float* Wr   = (const float*)d_in[4];
  const float* br   = (const float*)d_in[5];
  const float* att  = (const float*)d_in[6];
  const float* bout = (const float*)d_in[7];
  const float* gtok = (const float*)d_in[8];
  const float* m1pw = (const float*)d_in[9];
  const float* m1pb = (const float*)d_in[10];
  const float* m1w1 = (const float*)d_in[11];
  const float* m1b1 = (const float*)d_in[12];
  const float* m1w2 = (const float*)d_in[13];
  const float* m1b2 = (const float*)d_in[14];
  const float* bn1g = (const float*)d_in[15];
  const float* bn1b = (const float*)d_in[16];
  const float* m2w1 = (const float*)d_in[17];
  const float* m2b1 = (const float*)d_in[18];
  const float* m2w2 = (const float*)d_in[19];
  const float* m2b2 = (const float*)d_in[20];
  const float* bn2g = (const float*)d_in[21];
  const float* bn2b = (const float*)d_in[22];
  const float* m3pw = (const float*)d_in[23];
  const float* m3pb = (const float*)d_in[24];
  const float* m3w1 = (const float*)d_in[25];
  const float* m3b1 = (const float*)d_in[26];
  const float* m3w2 = (const float*)d_in[27];
  const float* m3b2 = (const float*)d_in[28];
  const int*   batch= (const int*)d_in[29];

  float* gout = (float*)d_out;              // [3][512][256]
  float* hout = (float*)d_out + 393216;     // [512][256]

  char* w = (char*)d_ws;
  __hip_bfloat16* wlt = (__hip_bfloat16*)(w + 0);   // 393216 B
  float*    cvec = (float*)(w + 393216);
  float*    ebuf = (float*)(w + 396288);
  // zero region (398336 floats):
  float*    gacc = (float*)(w + 2796288);
  float*    den  = (float*)(w + 4369152);
  unsigned* mkey = (unsigned*)(w + 4375296);
  float*    bns  = (float*)(w + 4381440);
  // head temps:
  float*    T1   = (float*)(w + 4389632);
  float*    P1   = (float*)(w + 5438208);
  float*    Hm   = (float*)(w + 6486784);
  float*    T2   = (float*)(w + 7535360);
  float*    H2   = (float*)(w + 8583936);
  float*    T3   = (float*)(w + 9632512);
  float*    P3   = (float*)(w + 10156800);

  kprep<<<435, 256, 0, stream>>>(Wl, wlt, Wr, bl, br, gtok, cvec, gacc);
  k1<<<256, 512, 0, stream>>>(x, wlt, cvec, att, batch, ebuf, mkey);
  kscan<<<dim3(782, 3), 256, 0, stream>>>(x, Wl, cvec, att, batch, ebuf, mkey, den, gacc);
  kgfinal<<<1536, 256, 0, stream>>>(gacc, den, bl, bout, gout);
  // S1: T1 = tanh(h0@m1w1+b1), P1 = h0@m1pw+pb  (gathered h0), K=832
  kmfma<<<dim3(8,8,2), 256, 0, stream>>>(nullptr, nullptr, ga, gout,
      nullptr, nullptr, nullptr, nullptr,
      m1w1, m1b1, T1, 1, m1pw, m1pb, P1, 0, 512, 832, 1, 0);
  // S2: Hm = T1@m1w2 + b2 + P1, bn1 stats
  kmfma<<<dim3(8,8,1), 256, 0, stream>>>(T1, P1, nullptr, nullptr,
      nullptr, nullptr, nullptr, bns,
      m1w2, m1b2, Hm, 0, nullptr, nullptr, nullptr, 0, 512, 512, 0, 1);
  // S3: T2 = tanh( tanh(bn1(Hm)) @ m2w1 + b1 )
  kmfma<<<dim3(8,8,1), 256, 0, stream>>>(Hm, nullptr, nullptr, nullptr,
      bns, bn1g, bn1b, nullptr,
      m2w1, m2b1, T2, 1, nullptr, nullptr, nullptr, 0, 512, 512, 2, 0);
  // S4: H2 = T2@m2w2 + b2 + tanh(bn1(Hm)), bn2 stats
  kmfma<<<dim3(8,8,1), 256, 0, stream>>>(T2, Hm, nullptr, nullptr,
      bns, bn1g, bn1b, bns + 1024,
      m2w2, m2b2, H2, 0, nullptr, nullptr, nullptr, 0, 512, 512, 0, 2);
  // S5: A = tanh(bn2(H2)); T3 = tanh(A@m3w1+b1), P3 = A@m3pw+pb  (N=256)
  kmfma<<<dim3(4,8,2), 256, 0, stream>>>(H2, nullptr, nullptr, nullptr,
      bns + 1024, bn2g, bn2b, nullptr,
      m3w1, m3b1, T3, 1, m3pw, m3pb, P3, 0, 256, 512, 2, 0);
  // S6: hout = T3@m3w2 + b2 + P3  (K=256)
  kmfma<<<dim3(4,8,1), 256, 0, stream>>>(T3, P3, nullptr, nullptr,
      nullptr, nullptr, nullptr, nullptr,
      m3w2, m3b2, hout, 0, nullptr, nullptr, nullptr, 0, 256, 256, 0, 1);
}